// Round 4
// baseline (1119.794 us; speedup 1.0000x reference)
//
#include <hip/hip_runtime.h>
#include <math.h>

#define BN 4
#define NN 2048
#define DD 256
#define EPSF 1e-5f

typedef __attribute__((ext_vector_type(8))) short bf16x8;
typedef __attribute__((ext_vector_type(4))) float f32x4;

// ---- output layout (float offsets) ----
constexpr size_t OFF_EST = 0;                                  // (B,2,N,D)
constexpr size_t OFF_OUT = (size_t)BN * 2 * NN * DD;           // (B,2,N,D)
constexpr size_t OFF_QIJ = OFF_OUT + (size_t)BN * 2 * NN * DD; // (B,2,N,N)
constexpr size_t OFF_VV  = OFF_QIJ + (size_t)BN * 2 * NN * NN; // (1,2,N,D)
constexpr size_t OFF_UV  = OFF_VV + (size_t)2 * NN * DD;       // (B,2,N,D)
constexpr size_t OFF_LH  = OFF_UV + (size_t)BN * 2 * NN * DD;  // (2,D,1)

// ---- scratch regions (Q_ij imaginary channels; zeroed before return) ----
constexpr size_t SCR_B0   = OFF_QIJ + (size_t)NN * NN;         // b0-imag
constexpr size_t U_Q16    = 0;
constexpr size_t U_K16    = (size_t)BN * NN * DD;
constexpr size_t U_VT16   = 2 * (size_t)BN * NN * DD;
constexpr size_t SCR_QN   = SCR_B0 + 3 * (size_t)BN * NN * DD / 2;
constexpr size_t SCR_KN   = SCR_QN + (size_t)BN * NN;
constexpr size_t SCR_L    = SCR_KN + (size_t)BN * NN;
constexpr size_t SCR_SC   = SCR_L + (size_t)BN * NN;   // [tau2, s, ga_bar, om_bar, _, _, _, _, barrier cnt, barrier gen]
constexpr size_t SCR_W16P = SCR_SC + 16;
constexpr size_t SCR_E16F = OFF_QIJ + 3 * (size_t)NN * NN;     // b1-imag
constexpr size_t U_PART   = (size_t)BN * NN * 512;
constexpr size_t SCR_Z16F = OFF_QIJ + 5 * (size_t)NN * NN;     // b2-imag
constexpr size_t SCR_Z16VF = OFF_QIJ + 7 * (size_t)NN * NN;    // b3-imag
constexpr size_t U_W16    = (size_t)BN * NN * 512;
constexpr size_t W16_PER_B = 136 * 16384;

#define NBLK 512

__device__ __forceinline__ short f2bf(float x) {
    union { float f; unsigned u; } v; v.f = x;
    unsigned r = v.u + 0x7fff + ((v.u >> 16) & 1);
    return (short)(r >> 16);
}
__device__ __forceinline__ float bf2f(unsigned short h) {
    union { unsigned u; float f; } v; v.u = ((unsigned)h) << 16;
    return v.f;
}
__device__ __forceinline__ unsigned short* u16p(float* d, size_t fofs) {
    return (unsigned short*)(d + fofs);
}
__device__ __forceinline__ const unsigned short* u16pc(const float* d, size_t fofs) {
    return (const unsigned short*)(d + fofs);
}
__device__ __forceinline__ unsigned short* w16p(float* d, int b) {
    return (b < 3) ? u16p(d, SCR_Z16F) + (size_t)b * W16_PER_B
                   : u16p(d, SCR_Z16VF);
}
__device__ __forceinline__ const unsigned short* w16pc(const float* d, int b) {
    return (b < 3) ? u16pc(d, SCR_Z16F) + (size_t)b * W16_PER_B
                   : u16pc(d, SCR_Z16VF);
}
__device__ __forceinline__ int nc_of(int TI) { return TI >= 12 ? 3 : (TI >= 6 ? 2 : 1); }
__device__ __forceinline__ int cb_of(int TI) {
    return TI < 6 ? TI : (TI < 12 ? 6 + 2 * (TI - 6) : 18 + 3 * (TI - 12));
}

// hand-rolled grid barrier (all NBLK blocks co-resident by launch_bounds(256,2)).
// agent-scope atomics are cross-XCD coherent; __threadfence() = agent fence
// (buffer_wbl2 on release side / buffer_inv on acquire side on gfx950).
__device__ __forceinline__ void gbar(float* dout) {
    __syncthreads();
    if (threadIdx.x == 0) {
        unsigned* cnt = (unsigned*)(dout + SCR_SC + 8);
        unsigned* gen = cnt + 1;
        __threadfence();
        unsigned g = __hip_atomic_load(gen, __ATOMIC_RELAXED, __HIP_MEMORY_SCOPE_AGENT);
        unsigned a = __hip_atomic_fetch_add(cnt, 1u, __ATOMIC_ACQ_REL, __HIP_MEMORY_SCOPE_AGENT);
        if (a == (unsigned)NBLK - 1) {
            __hip_atomic_store(cnt, 0u, __ATOMIC_RELAXED, __HIP_MEMORY_SCOPE_AGENT);
            __hip_atomic_fetch_add(gen, 1u, __ATOMIC_RELEASE, __HIP_MEMORY_SCOPE_AGENT);
        } else {
            while (__hip_atomic_load(gen, __ATOMIC_ACQUIRE, __HIP_MEMORY_SCOPE_AGENT) == g)
                __builtin_amdgcn_s_sleep(2);
        }
        __threadfence();
    }
    __syncthreads();
}

// async global->LDS, 16B per lane (m97 pattern)
__device__ __forceinline__ void gll16(const unsigned short* g, short* l) {
    __builtin_amdgcn_global_load_lds(
        (const __attribute__((address_space(1))) unsigned*)g,
        (__attribute__((address_space(3))) unsigned*)l, 16, 0, 0);
}
// stage a 128x32 bf16 tile into ldsbuf[128*32] (linear), 256 threads
__device__ __forceinline__ void stage_tile(const unsigned short* gbase, size_t stride_sh,
                                           short* ldsbuf, int t) {
    const int w = t >> 6, L = t & 63;
#pragma unroll
    for (int p = 0; p < 2; ++p) {
        const int r0 = w * 32 + p * 16;
        const unsigned short* src = gbase + (size_t)(r0 + (L >> 2)) * stride_sh + (L & 3) * 8;
        gll16(src, ldsbuf + r0 * 32);
    }
}

// =====================================================================
// single persistent mega-kernel: all phases, hand-rolled grid barrier
// grid 512 x 256 thr, 2 blocks/CU guaranteed (LDS 16.6KB, VGPR<=256)
// =====================================================================
__global__ __launch_bounds__(256, 2) void k_mega(
    const float* __restrict__ Zq, const float* __restrict__ Zk,
    const float* __restrict__ Zv, const float* __restrict__ tmeas,
    const float* __restrict__ Wq, const float* __restrict__ bq,
    const float* __restrict__ Wk, const float* __restrict__ bk,
    const float* __restrict__ Wv, const float* __restrict__ bv,
    const float* __restrict__ Wp, const float* __restrict__ bp,
    const float* __restrict__ lamOm, const float* __restrict__ lamGa,
    const float* __restrict__ tau, const float* __restrict__ delta,
    const float* __restrict__ lamC, float* __restrict__ dout)
{
    __shared__ __align__(16) float smemf[4160];   // 16640 B: Al|Bl (16KB) or T[64][65]
    short* Al = (short*)smemf;
    short* Bl = ((short*)smemf) + 4096;

    const int t = threadIdx.x;
    const int wave = t >> 6, lane = t & 63, quad = lane >> 4, lm = lane & 15;
    const int wm = (wave >> 1) * 64, wn = (wave & 1) * 64;

    // ================= P0: cvt + independent fills + scalars =================
    {
        const long tid = (long)blockIdx.x * 256 + t;
        const long nthr = (long)gridDim.x * 256;
        // Z tensors -> bf16 [b][n][512]
        for (long u = tid; u < 3L * 1048576; u += nthr) {
            const int zz = (int)(u >> 20);
            const long i4 = u & 1048575;
            const float* Z = (zz == 0) ? Zq : (zz == 1) ? Zk : Zv;
            unsigned short* O = (zz == 0) ? u16p(dout, SCR_Z16F)
                              : (zz == 1) ? u16p(dout, SCR_Z16F) + (size_t)BN * NN * 512
                                          : u16p(dout, SCR_Z16VF);
            const long i = i4 * 4;
            const int d = (int)(i & (DD - 1));
            const long r = i >> 8;
            const int n = (int)(r & (NN - 1));
            const long bc = r >> 11;
            const int c = (int)(bc & 1), b = (int)(bc >> 1);
            float4 v = *(const float4*)&Z[i];
            ushort4 o;
            o.x = (unsigned short)f2bf(v.x); o.y = (unsigned short)f2bf(v.y);
            o.z = (unsigned short)f2bf(v.z); o.w = (unsigned short)f2bf(v.w);
            *(ushort4*)&O[((size_t)(b * NN + n)) * 512 + c * 256 + d] = o;
        }
        // weights -> 6 bf16 mats [d][512]
        for (long e4 = tid; e4 < 196608; e4 += nthr) {
            const long e = e4 * 4;
            const int k = (int)(e & 511);
            const long rest = e >> 9;
            const int dd = (int)(rest & 255);
            const int m = (int)(rest >> 8);
            const float* Ws = (m == 0) ? Wq : (m == 1) ? Wk : (m <= 3) ? Wv : Wp;
            int mode;
            if (m < 3)      { mode = 0; }
            else if (m == 3){ mode = 1; }
            else            { mode = m - 4; }
            const int kc = k >> 8, kk = k & 255;
            int wc; float sgn;
            if (mode == 0) { wc = kc; sgn = kc ? -1.f : 1.f; }
            else           { wc = 1 - kc; sgn = 1.f; }
            float4 v = *(const float4*)&Ws[((size_t)wc * DD + dd) * DD + kk];
            ushort4 o;
            o.x = (unsigned short)f2bf(sgn * v.x); o.y = (unsigned short)f2bf(sgn * v.y);
            o.z = (unsigned short)f2bf(sgn * v.z); o.w = (unsigned short)f2bf(sgn * v.w);
            unsigned short* dst = (m < 4)
                ? u16p(dout, SCR_Z16VF) + U_W16 + (size_t)m * 131072
                : u16p(dout, SCR_W16P) + (size_t)(m - 4) * 131072;
            *(ushort4*)&dst[(size_t)dd * 512 + k] = o;
        }
        // structural fills: VV ch0 ones, VV ch1 zero, UV ch1 zero x4, LH zero
        const float4 ones = {1.f, 1.f, 1.f, 1.f};
        const float4 zz4 = {0.f, 0.f, 0.f, 0.f};
        float* VV0 = dout + OFF_VV;
        for (long u = tid; u < 131072; u += nthr) *(float4*)&VV0[u * 4] = ones;
        float* VV1 = dout + OFF_VV + (size_t)NN * DD;
        for (long u = tid; u < 131072; u += nthr) *(float4*)&VV1[u * 4] = zz4;
        for (int b = 0; b < BN; ++b) {
            float* U1 = dout + OFF_UV + (size_t)(2 * b + 1) * NN * DD;
            for (long u = tid; u < 131072; u += nthr) *(float4*)&U1[u * 4] = zz4;
        }
        float* LH = dout + OFF_LH;
        for (long u = tid; u < 128; u += nthr) *(float4*)&LH[u * 4] = zz4;
        // zero QN/KN/L (24576 floats = 6144 f4)
        for (long u = tid; u < 6144; u += nthr) *(float4*)&dout[SCR_QN + u * 4] = zz4;
        // scalars (block 0)
        if (blockIdx.x == 0) {
            float* red = smemf;  // reuse LDS
            float c2 = lamC[t] * lamC[t];
            float ga = c2 * (lamGa[t] * lamGa[t] + EPSF);
            float om = c2 * (lamOm[t] * lamOm[t] + EPSF);
            for (int o = 32; o > 0; o >>= 1) {
                ga += __shfl_down(ga, o, 64);
                om += __shfl_down(om, o, 64);
            }
            if ((t & 63) == 0) { red[t >> 6] = ga; red[4 + (t >> 6)] = om; }
            __syncthreads();
            if (t == 0) {
                float gs = red[0] + red[1] + red[2] + red[3];
                float os = red[4] + red[5] + red[6] + red[7];
                float* scal = dout + SCR_SC;
                scal[0] = tau[0] * tau[0];
                scal[1] = 1.f / (1.f + __expf(-delta[0]));
                scal[2] = gs / 256.f;
                scal[3] = os / 256.f;
            }
        }
    }
    gbar(dout);

    // ================= P1: QKV projections (512 jobs) =================
    {
        const int job = blockIdx.x;
        const int z = job >> 7;
        const int rem = job & 127;
        const int d0 = (rem & 1) * 128;
        const int by = rem >> 1;
        const int b = by >> 4;
        const int n0 = (by & 15) * 128;

        const unsigned short* Z16 =
            (z == 0) ? u16pc(dout, SCR_Z16F)
          : (z == 1) ? u16pc(dout, SCR_Z16F) + (size_t)BN * NN * 512
                     : u16pc(dout, SCR_Z16VF);
        const unsigned short* W16 = u16pc(dout, SCR_Z16VF) + U_W16 + (size_t)z * 131072;
        const float* bias = (z == 0) ? bq : (z == 1) ? bk : bv;
        const int bofs = (z == 3) ? DD : 0;
        const unsigned short* Abase = Z16 + (size_t)(b * NN + n0) * 512;
        const unsigned short* Bbase = W16 + (size_t)d0 * 512;

        f32x4 acc[4][4];
#pragma unroll
        for (int i = 0; i < 4; ++i)
#pragma unroll
            for (int j = 0; j < 4; ++j) acc[i][j] = (f32x4){0.f, 0.f, 0.f, 0.f};

        for (int kt = 0; kt < 16; ++kt) {
            const int kk0 = kt * 32;
            stage_tile(Abase + kk0, 512, Al, t);
            stage_tile(Bbase + kk0, 512, Bl, t);
            __syncthreads();
            bf16x8 af[4], bff[4];
#pragma unroll
            for (int mi = 0; mi < 4; ++mi) af[mi] = *(const bf16x8*)&Al[(wm + mi * 16 + lm) * 32 + quad * 8];
#pragma unroll
            for (int nj = 0; nj < 4; ++nj) bff[nj] = *(const bf16x8*)&Bl[(wn + nj * 16 + lm) * 32 + quad * 8];
#pragma unroll
            for (int mi = 0; mi < 4; ++mi)
#pragma unroll
                for (int nj = 0; nj < 4; ++nj)
                    acc[mi][nj] = __builtin_amdgcn_mfma_f32_16x16x32_bf16(af[mi], bff[nj], acc[mi][nj], 0, 0, 0);
            __syncthreads();
        }

        if (z <= 1) {
            unsigned short* O16 = u16p(dout, SCR_B0) + (z ? U_K16 : U_Q16) + (size_t)b * NN * DD;
            float* NRM = dout + (z ? SCR_KN : SCR_QN) + b * NN;
#pragma unroll
            for (int mi = 0; mi < 4; ++mi)
#pragma unroll
                for (int r = 0; r < 4; ++r) {
                    const int m = n0 + wm + mi * 16 + quad * 4 + r;
                    float ss = 0.f;
#pragma unroll
                    for (int nj = 0; nj < 4; ++nj) {
                        const int d = d0 + wn + nj * 16 + lm;
                        unsigned short h = (unsigned short)f2bf(acc[mi][nj][r] + bias[d]);
                        O16[(size_t)m * DD + d] = h;
                        const float vb = bf2f(h);
                        ss = fmaf(vb, vb, ss);
                    }
                    ss += __shfl_down(ss, 8, 16); ss += __shfl_down(ss, 4, 16);
                    ss += __shfl_down(ss, 2, 16); ss += __shfl_down(ss, 1, 16);
                    if (lm == 0) atomicAdd(&NRM[m], ss);
                }
        } else if (z == 2) {
            float* UV0 = dout + OFF_UV + (size_t)(b * 2) * NN * DD;
#pragma unroll
            for (int mi = 0; mi < 4; ++mi)
#pragma unroll
                for (int r = 0; r < 4; ++r) {
                    const int m = n0 + wm + mi * 16 + quad * 4 + r;
#pragma unroll
                    for (int nj = 0; nj < 4; ++nj) {
                        const int d = d0 + wn + nj * 16 + lm;
                        UV0[(size_t)m * DD + d] = acc[mi][nj][r] + bias[d];
                    }
                }
        } else {
            const float s1 = 1.f - dout[SCR_SC + 1];
            float* EST1 = dout + OFF_EST + (size_t)(b * 2 + 1) * NN * DD;
            unsigned short* E16 = u16p(dout, SCR_E16F) + (size_t)b * NN * 512;
#pragma unroll
            for (int mi = 0; mi < 4; ++mi)
#pragma unroll
                for (int r = 0; r < 4; ++r) {
                    const int m = n0 + wm + mi * 16 + quad * 4 + r;
#pragma unroll
                    for (int nj = 0; nj < 4; ++nj) {
                        const int d = d0 + wn + nj * 16 + lm;
                        const float v = s1 * (acc[mi][nj][r] + bias[bofs + d]);
                        EST1[(size_t)m * DD + d] = v;
                        E16[(size_t)m * 512 + 256 + d] = (unsigned short)f2bf(v);
                    }
                }
        }
    }
    gbar(dout);

    // ================= P2: V transpose (512 jobs) =================
    {
        float (*T)[65] = (float(*)[65])smemf;
        const int job = blockIdx.x;
        const int b = job >> 7, rem = job & 127;
        const int db = (rem >> 5) * 64, nb = (rem & 31) * 64;
        const float* V = dout + OFF_UV + (size_t)(b * 2) * NN * DD;
        unsigned short* VT = u16p(dout, SCR_B0) + U_VT16 + (size_t)b * DD * NN;
        const int tr = t >> 4, tc = (t & 15) * 4;
#pragma unroll
        for (int p = 0; p < 4; ++p) {
            float4 v = *(const float4*)&V[(size_t)(nb + tr + p * 16) * DD + db + tc];
            T[tr + p * 16][tc + 0] = v.x; T[tr + p * 16][tc + 1] = v.y;
            T[tr + p * 16][tc + 2] = v.z; T[tr + p * 16][tc + 3] = v.w;
        }
        __syncthreads();
#pragma unroll
        for (int p = 0; p < 4; ++p) {
            const int d = tr + p * 16;
            ushort4 o;
            o.x = (unsigned short)f2bf(T[tc + 0][d]);
            o.y = (unsigned short)f2bf(T[tc + 1][d]);
            o.z = (unsigned short)f2bf(T[tc + 2][d]);
            o.w = (unsigned short)f2bf(T[tc + 3][d]);
            *(ushort4*)&VT[(size_t)(db + d) * NN + nb + tc] = o;
        }
        __syncthreads();
    }
    gbar(dout);

    // ================= P3: causal scores (544 jobs) =================
    for (int xj = blockIdx.x; xj < 544; xj += gridDim.x) {
        const int b = xj / 136, x = xj % 136;
        int ti = (int)((sqrtf(8.f * x + 1.f) - 1.f) * 0.5f);
        while ((ti + 1) * (ti + 2) / 2 <= x) ++ti;
        while (ti * (ti + 1) / 2 > x) --ti;
        const int tj = x - ti * (ti + 1) / 2;
        const int i0 = ti * 128, j0 = tj * 128;
        const unsigned short* Q16 = u16pc(dout, SCR_B0) + U_Q16 + (size_t)b * NN * DD;
        const unsigned short* K16 = u16pc(dout, SCR_B0) + U_K16 + (size_t)b * NN * DD;
        const unsigned short* Abase = Q16 + (size_t)i0 * DD;
        const unsigned short* Bbase = K16 + (size_t)j0 * DD;

        f32x4 acc[4][4];
#pragma unroll
        for (int i = 0; i < 4; ++i)
#pragma unroll
            for (int j = 0; j < 4; ++j) acc[i][j] = (f32x4){0.f, 0.f, 0.f, 0.f};

        for (int kt = 0; kt < 8; ++kt) {
            const int kk0 = kt * 32;
            stage_tile(Abase + kk0, DD, Al, t);
            stage_tile(Bbase + kk0, DD, Bl, t);
            __syncthreads();
            bf16x8 af[4], bff[4];
#pragma unroll
            for (int mi = 0; mi < 4; ++mi) af[mi] = *(const bf16x8*)&Al[(wm + mi * 16 + lm) * 32 + quad * 8];
#pragma unroll
            for (int nj = 0; nj < 4; ++nj) bff[nj] = *(const bf16x8*)&Bl[(wn + nj * 16 + lm) * 32 + quad * 8];
#pragma unroll
            for (int mi = 0; mi < 4; ++mi)
#pragma unroll
                for (int nj = 0; nj < 4; ++nj)
                    acc[mi][nj] = __builtin_amdgcn_mfma_f32_16x16x32_bf16(af[mi], bff[nj], acc[mi][nj], 0, 0, 0);
            __syncthreads();
        }

        const float tau2 = dout[SCR_SC + 0], ga = dout[SCR_SC + 2], om = dout[SCR_SC + 3];
        unsigned short* WT = w16p(dout, b) + (size_t)x * 16384;
        const float* QN_ = dout + SCR_QN + b * NN;
        const float* KN_ = dout + SCR_KN + b * NN;
        float kn[4], tjv[4]; int jj[4];
#pragma unroll
        for (int nj = 0; nj < 4; ++nj) {
            jj[nj] = j0 + wn + nj * 16 + lm;
            kn[nj] = KN_[jj[nj]];
            tjv[nj] = tmeas[jj[nj]];
        }
#pragma unroll
        for (int mi = 0; mi < 4; ++mi)
#pragma unroll
            for (int r = 0; r < 4; ++r) {
                const int li = wm + mi * 16 + quad * 4 + r;
                const int i = i0 + li;
                const float qni = QN_[i], tqi = tmeas[i];
                float rs = 0.f;
#pragma unroll
                for (int nj = 0; nj < 4; ++nj) {
                    float xx = ga + om * fabsf(tqi - tjv[nj]) + qni + kn[nj] - 2.f * acc[mi][nj][r];
                    xx = fmaxf(xx, 1e-30f);
                    float w = (tau2 == 1.f) ? __builtin_amdgcn_rcpf(xx)
                                            : __expf(-tau2 * __logf(xx));
                    if (jj[nj] > i) w = 0.f;
                    const unsigned short h = (unsigned short)f2bf(w);
                    WT[(size_t)li * 128 + (wn + nj * 16 + lm)] = h;
                    rs += bf2f(h);
                }
                rs += __shfl_down(rs, 8, 16); rs += __shfl_down(rs, 4, 16);
                rs += __shfl_down(rs, 2, 16); rs += __shfl_down(rs, 1, 16);
                if (lm == 0) atomicAdd(&dout[SCR_L + b * NN + i], rs);
            }
    }
    gbar(dout);

    // ================= P4: est_inner GEMM (240 jobs) =================
    for (int job = blockIdx.x; job < 240; job += gridDim.x) {
        const int b = job / 60, xx = job % 60;
        const int chunk = xx >> 1, half = xx & 1;
        int y = chunk, TI = 0, cb = 0;
        for (;;) { const int nc = nc_of(TI); if (y < nc) break; y -= nc; cb += nc; ++TI; }
        const int kbeg = y * 768;
        const int kend = min(kbeg + 768, (TI + 1) * 128);
        const int nst = (kend - kbeg) >> 5;
        const int cidx = cb + y;
        const int tri = TI * (TI + 1) / 2;
        const unsigned short* WT = w16pc(dout, b);
        const unsigned short* VT = u16pc(dout, SCR_B0) + U_VT16 + (size_t)b * DD * NN
                                 + (size_t)(half * 128) * NN;

        f32x4 acc[4][4];
#pragma unroll
        for (int i = 0; i < 4; ++i)
#pragma unroll
            for (int j = 0; j < 4; ++j) acc[i][j] = (f32x4){0.f, 0.f, 0.f, 0.f};

        for (int kt = 0; kt < nst; ++kt) {
            const int kk0 = kbeg + kt * 32;
            const int tile = kk0 >> 7;
            stage_tile(WT + (size_t)(tri + tile) * 16384 + (kk0 & 127), 128, Al, t);
            stage_tile(VT + kk0, NN, Bl, t);
            __syncthreads();
            bf16x8 af[4], bff[4];
#pragma unroll
            for (int mi = 0; mi < 4; ++mi) af[mi] = *(const bf16x8*)&Al[(wm + mi * 16 + lm) * 32 + quad * 8];
#pragma unroll
            for (int nj = 0; nj < 4; ++nj) bff[nj] = *(const bf16x8*)&Bl[(wn + nj * 16 + lm) * 32 + quad * 8];
#pragma unroll
            for (int mi = 0; mi < 4; ++mi)
#pragma unroll
                for (int nj = 0; nj < 4; ++nj)
                    acc[mi][nj] = __builtin_amdgcn_mfma_f32_16x16x32_bf16(af[mi], bff[nj], acc[mi][nj], 0, 0, 0);
            __syncthreads();
        }
        unsigned short* P = u16p(dout, SCR_E16F) + U_PART +
                            ((size_t)(b * 30 + cidx)) * 128 * 256;
#pragma unroll
        for (int mi = 0; mi < 4; ++mi)
#pragma unroll
            for (int r = 0; r < 4; ++r) {
                const int ri = wm + mi * 16 + quad * 4 + r;
#pragma unroll
                for (int nj = 0; nj < 4; ++nj) {
                    const int d = half * 128 + wn + nj * 16 + lm;
                    P[(size_t)ri * 256 + d] = (unsigned short)f2bf(acc[mi][nj][r]);
                }
            }
    }
    gbar(dout);

    // ================= P5: blend (2048) + Qij rows (8192) =================
    for (int job = blockIdx.x; job < 10240; job += gridDim.x) {
        if (job < 2048) {
            const int b = job >> 9, x = job & 511;
            const int i = x * 4 + (t >> 6);
            const int d4 = (t & 63) * 4;
            const int TI = i >> 7;
            const int nc = nc_of(TI), cb = cb_of(TI);
            const float s = dout[SCR_SC + 1];
            const float linv = 1.f / dout[SCR_L + b * NN + i];
            const unsigned short* P = u16pc(dout, SCR_E16F) + U_PART;
            float4 sum = {0.f, 0.f, 0.f, 0.f};
            for (int c = 0; c < nc; ++c) {
                ushort4 pv = *(const ushort4*)&P[((size_t)(b * 30 + cb + c) * 128 + (i & 127)) * 256 + d4];
                sum.x += bf2f(pv.x); sum.y += bf2f(pv.y);
                sum.z += bf2f(pv.z); sum.w += bf2f(pv.w);
            }
            const float4 vr = *(const float4*)&dout[OFF_UV + ((size_t)(b * 2) * NN + i) * DD + d4];
            const float sl = s * linv;
            float4 ev;
            ev.x = (1.f - s) * vr.x + sl * sum.x;
            ev.y = (1.f - s) * vr.y + sl * sum.y;
            ev.z = (1.f - s) * vr.z + sl * sum.z;
            ev.w = (1.f - s) * vr.w + sl * sum.w;
            *(float4*)&dout[OFF_EST + ((size_t)(b * 2) * NN + i) * DD + d4] = ev;
            ushort4 o;
            o.x = (unsigned short)f2bf(ev.x); o.y = (unsigned short)f2bf(ev.y);
            o.z = (unsigned short)f2bf(ev.z); o.w = (unsigned short)f2bf(ev.w);
            *(ushort4*)&u16p(dout, SCR_E16F)[((size_t)(b * NN + i)) * 512 + d4] = o;
        } else {
            const int jj = job - 2048;
            const int b = jj >> 11, i = jj & 2047;
            const int TI = i >> 7, li = i & 127;
            const int tri = TI * (TI + 1) / 2;
            const float linv = 1.f / dout[SCR_L + b * NN + i];
            const unsigned short* WTb = w16pc(dout, b);
            float* row = dout + OFF_QIJ + (size_t)b * 2 * NN * NN + (size_t)i * NN;
            for (int j4 = t * 4; j4 < NN; j4 += 1024) {
                const int tj = j4 >> 7;
                float4 o = {0.f, 0.f, 0.f, 0.f};
                if (tj <= TI) {
                    ushort4 h = *(const ushort4*)&WTb[((size_t)(tri + tj)) * 16384
                                                      + (size_t)li * 128 + (j4 & 127)];
                    o.x = bf2f(h.x) * linv; o.y = bf2f(h.y) * linv;
                    o.z = bf2f(h.z) * linv; o.w = bf2f(h.w) * linv;
                }
                *(float4*)&row[j4] = o;
            }
        }
    }
    gbar(dout);

    // ================= P6: output projection (256 jobs) =================
    {
        const int job = blockIdx.x;
        if (job < 256) {
            const int z = job >> 7;
            const int rem = job & 127;
            const int d0 = (rem & 1) * 128;
            const int by = rem >> 1;
            const int b = by >> 4;
            const int n0 = (by & 15) * 128;
            const unsigned short* E16 = u16pc(dout, SCR_E16F) + (size_t)b * NN * 512;
            const unsigned short* W16 = u16pc(dout, SCR_W16P) + (size_t)z * 131072;
            const unsigned short* Abase = E16 + (size_t)n0 * 512;
            const unsigned short* Bbase = W16 + (size_t)d0 * 512;

            f32x4 acc[4][4];
#pragma unroll
            for (int i = 0; i < 4; ++i)
#pragma unroll
                for (int j = 0; j < 4; ++j) acc[i][j] = (f32x4){0.f, 0.f, 0.f, 0.f};

            for (int kt = 0; kt < 16; ++kt) {
                const int kk0 = kt * 32;
                stage_tile(Abase + kk0, 512, Al, t);
                stage_tile(Bbase + kk0, 512, Bl, t);
                __syncthreads();
                bf16x8 af[4], bff[4];
#pragma unroll
                for (int mi = 0; mi < 4; ++mi) af[mi] = *(const bf16x8*)&Al[(wm + mi * 16 + lm) * 32 + quad * 8];
#pragma unroll
                for (int nj = 0; nj < 4; ++nj) bff[nj] = *(const bf16x8*)&Bl[(wn + nj * 16 + lm) * 32 + quad * 8];
#pragma unroll
                for (int mi = 0; mi < 4; ++mi)
#pragma unroll
                    for (int nj = 0; nj < 4; ++nj)
                        acc[mi][nj] = __builtin_amdgcn_mfma_f32_16x16x32_bf16(af[mi], bff[nj], acc[mi][nj], 0, 0, 0);
                __syncthreads();
            }
            const int bofs = z ? DD : 0;
            float* O = dout + OFF_OUT + (size_t)(b * 2 + z) * NN * DD;
#pragma unroll
            for (int mi = 0; mi < 4; ++mi)
#pragma unroll
                for (int r = 0; r < 4; ++r) {
                    const int m = n0 + wm + mi * 16 + quad * 4 + r;
#pragma unroll
                    for (int nj = 0; nj < 4; ++nj) {
                        const int d = d0 + wn + nj * 16 + lm;
                        O[(size_t)m * DD + d] = acc[mi][nj][r] + bp[bofs + d];
                    }
                }
        }
    }
}

extern "C" void kernel_launch(void* const* d_in, const int* in_sizes, int n_in,
                              void* d_out, int out_size, void* d_ws, size_t ws_size,
                              hipStream_t stream) {
    const float* Zq = (const float*)d_in[0];
    const float* Zk = (const float*)d_in[1];
    const float* Zv = (const float*)d_in[2];
    const float* tm = (const float*)d_in[3];
    const float* Wq = (const float*)d_in[4];
    const float* bq = (const float*)d_in[5];
    const float* Wk = (const float*)d_in[6];
    const float* bk = (const float*)d_in[7];
    const float* Wv = (const float*)d_in[8];
    const float* bv = (const float*)d_in[9];
    const float* Wp = (const float*)d_in[10];
    const float* bp = (const float*)d_in[11];
    const float* lamOm = (const float*)d_in[13];
    const float* lamGa = (const float*)d_in[14];
    const float* tau = (const float*)d_in[15];
    const float* delta = (const float*)d_in[16];
    const float* lamC = (const float*)d_in[17];
    float* out = (float*)d_out;

    // zero the grid-barrier words (poison-proof), then one persistent kernel
    hipMemsetAsync((void*)(out + SCR_SC + 8), 0, 8, stream);
    k_mega<<<dim3(NBLK), dim3(256), 0, stream>>>(
        Zq, Zk, Zv, tm, Wq, bq, Wk, bk, Wv, bv, Wp, bp,
        lamOm, lamGa, tau, delta, lamC, out);

    // scratch cleanup: the 4 Q_ij imaginary channels (each NN*NN floats).
    // b0-imag covers Q16/K16/VT16 + QN/KN/L/SC(+barrier words)/W16P tail.
    hipMemsetAsync((void*)(out + SCR_B0),    0, (size_t)NN * NN * 4, stream);
    hipMemsetAsync((void*)(out + SCR_E16F),  0, (size_t)NN * NN * 4, stream);
    hipMemsetAsync((void*)(out + SCR_Z16F),  0, (size_t)NN * NN * 4, stream);
    hipMemsetAsync((void*)(out + SCR_Z16VF), 0, (size_t)NN * NN * 4, stream);
}

// Round 5
// 690.222 us; speedup vs baseline: 1.6224x; 1.6224x over previous
//
#include <hip/hip_runtime.h>
#include <math.h>

#define BN 4
#define NN 2048
#define DD 256
#define EPSF 1e-5f

typedef __attribute__((ext_vector_type(8))) short bf16x8;
typedef __attribute__((ext_vector_type(4))) float f32x4;

// ---- output layout (float offsets) ----
constexpr size_t OFF_EST = 0;                                  // (B,2,N,D)
constexpr size_t OFF_OUT = (size_t)BN * 2 * NN * DD;           // (B,2,N,D)
constexpr size_t OFF_QIJ = OFF_OUT + (size_t)BN * 2 * NN * DD; // (B,2,N,N)
constexpr size_t OFF_VV  = OFF_QIJ + (size_t)BN * 2 * NN * NN; // (1,2,N,D)
constexpr size_t OFF_UV  = OFF_VV + (size_t)2 * NN * DD;       // (B,2,N,D)
constexpr size_t OFF_LH  = OFF_UV + (size_t)BN * 2 * NN * DD;  // (2,D,1)

// ---- scratch regions (Q_ij imaginary channels; zeroed before return) ----
constexpr size_t SCR_B0   = OFF_QIJ + (size_t)NN * NN;         // b0-imag
constexpr size_t U_Q16    = 0;
constexpr size_t U_K16    = (size_t)BN * NN * DD;
constexpr size_t U_VT16   = 2 * (size_t)BN * NN * DD;
constexpr size_t SCR_QN   = SCR_B0 + 3 * (size_t)BN * NN * DD / 2;
constexpr size_t SCR_KN   = SCR_QN + (size_t)BN * NN;
constexpr size_t SCR_L    = SCR_KN + (size_t)BN * NN;
constexpr size_t SCR_SC   = SCR_L + (size_t)BN * NN;   // [tau2, s, ga_bar, om_bar, _,_,_,_, bar-cnt, bar-gen]
constexpr size_t SCR_W16P = SCR_SC + 16;
constexpr size_t SCR_E16F = OFF_QIJ + 3 * (size_t)NN * NN;     // b1-imag
constexpr size_t U_PART   = (size_t)BN * NN * 512;
constexpr size_t SCR_Z16F = OFF_QIJ + 5 * (size_t)NN * NN;     // b2-imag
constexpr size_t SCR_Z16VF = OFF_QIJ + 7 * (size_t)NN * NN;    // b3-imag
constexpr size_t U_W16    = (size_t)BN * NN * 512;
constexpr size_t W16_PER_B = 136 * 16384;

#define NBLK 512

__device__ __forceinline__ short f2bf(float x) {
    union { float f; unsigned u; } v; v.f = x;
    unsigned r = v.u + 0x7fff + ((v.u >> 16) & 1);
    return (short)(r >> 16);
}
__device__ __forceinline__ float bf2f(unsigned short h) {
    union { unsigned u; float f; } v; v.u = ((unsigned)h) << 16;
    return v.f;
}
__device__ __forceinline__ unsigned short* u16p(float* d, size_t fofs) {
    return (unsigned short*)(d + fofs);
}
__device__ __forceinline__ const unsigned short* u16pc(const float* d, size_t fofs) {
    return (const unsigned short*)(d + fofs);
}
__device__ __forceinline__ unsigned short* w16p(float* d, int b) {
    return (b < 3) ? u16p(d, SCR_Z16F) + (size_t)b * W16_PER_B
                   : u16p(d, SCR_Z16VF);
}
__device__ __forceinline__ const unsigned short* w16pc(const float* d, int b) {
    return (b < 3) ? u16pc(d, SCR_Z16F) + (size_t)b * W16_PER_B
                   : u16pc(d, SCR_Z16VF);
}
__device__ __forceinline__ int nc_of(int TI) { return TI >= 12 ? 3 : (TI >= 6 ? 2 : 1); }
__device__ __forceinline__ int cb_of(int TI) {
    return TI < 6 ? TI : (TI < 12 ? 6 + 2 * (TI - 6) : 18 + 3 * (TI - 12));
}

// grid barrier, sense-reversing. KEY FIX vs r4: spin with RELAXED agent
// atomic loads (uncached read of the coherent point, NO buffer_inv per poll)
// and do cache maintenance exactly once per block per barrier:
// one release fence (wbl2) at entry, one acquire fence (inv) at exit.
// r4's per-poll ACQUIRE spin emitted buffer_inv every iteration -> L2
// invalidation storm -> MfmaUtil 1%, 908us. 
__device__ __forceinline__ void gbar(float* dout) {
    __syncthreads();
    if (threadIdx.x == 0) {
        unsigned* cnt = (unsigned*)(dout + SCR_SC + 8);
        unsigned* gen = cnt + 1;
        __builtin_amdgcn_fence(__ATOMIC_RELEASE, "agent");   // one wbl2, waits
        unsigned g = __hip_atomic_load(gen, __ATOMIC_RELAXED, __HIP_MEMORY_SCOPE_AGENT);
        unsigned a = __hip_atomic_fetch_add(cnt, 1u, __ATOMIC_RELAXED, __HIP_MEMORY_SCOPE_AGENT);
        if (a == (unsigned)NBLK - 1) {
            __hip_atomic_store(cnt, 0u, __ATOMIC_RELAXED, __HIP_MEMORY_SCOPE_AGENT);
            __hip_atomic_fetch_add(gen, 1u, __ATOMIC_RELEASE, __HIP_MEMORY_SCOPE_AGENT);
        } else {
            while (__hip_atomic_load(gen, __ATOMIC_RELAXED, __HIP_MEMORY_SCOPE_AGENT) == g)
                __builtin_amdgcn_s_sleep(4);
        }
        __builtin_amdgcn_fence(__ATOMIC_ACQUIRE, "agent");   // one inv
    }
    __syncthreads();
}

// async global->LDS, 16B per lane (m97 pattern)
__device__ __forceinline__ void gll16(const unsigned short* g, short* l) {
    __builtin_amdgcn_global_load_lds(
        (const __attribute__((address_space(1))) unsigned*)g,
        (__attribute__((address_space(3))) unsigned*)l, 16, 0, 0);
}
// stage a 128x32 bf16 tile into ldsbuf[128*32] (linear), 256 threads
__device__ __forceinline__ void stage_tile(const unsigned short* gbase, size_t stride_sh,
                                           short* ldsbuf, int t) {
    const int w = t >> 6, L = t & 63;
#pragma unroll
    for (int p = 0; p < 2; ++p) {
        const int r0 = w * 32 + p * 16;
        const unsigned short* src = gbase + (size_t)(r0 + (L >> 2)) * stride_sh + (L & 3) * 8;
        gll16(src, ldsbuf + r0 * 32);
    }
}

// =====================================================================
// single persistent mega-kernel: all phases, relaxed-spin grid barrier
// grid 512 x 256 thr, 2 blocks/CU guaranteed (LDS 16.6KB, VGPR<=256)
// =====================================================================
__global__ __launch_bounds__(256, 2) void k_mega(
    const float* __restrict__ Zq, const float* __restrict__ Zk,
    const float* __restrict__ Zv, const float* __restrict__ tmeas,
    const float* __restrict__ Wq, const float* __restrict__ bq,
    const float* __restrict__ Wk, const float* __restrict__ bk,
    const float* __restrict__ Wv, const float* __restrict__ bv,
    const float* __restrict__ Wp, const float* __restrict__ bp,
    const float* __restrict__ lamOm, const float* __restrict__ lamGa,
    const float* __restrict__ tau, const float* __restrict__ delta,
    const float* __restrict__ lamC, float* __restrict__ dout)
{
    __shared__ __align__(16) float smemf[4160];   // 16640 B: Al|Bl (16KB) or T[64][65]
    short* Al = (short*)smemf;
    short* Bl = ((short*)smemf) + 4096;

    const int t = threadIdx.x;
    const int wave = t >> 6, lane = t & 63, quad = lane >> 4, lm = lane & 15;
    const int wm = (wave >> 1) * 64, wn = (wave & 1) * 64;

    // ================= P0: cvt + independent fills + scalars =================
    {
        const long tid = (long)blockIdx.x * 256 + t;
        const long nthr = (long)gridDim.x * 256;
        // Z tensors -> bf16 [b][n][512]
        for (long u = tid; u < 3L * 1048576; u += nthr) {
            const int zz = (int)(u >> 20);
            const long i4 = u & 1048575;
            const float* Z = (zz == 0) ? Zq : (zz == 1) ? Zk : Zv;
            unsigned short* O = (zz == 0) ? u16p(dout, SCR_Z16F)
                              : (zz == 1) ? u16p(dout, SCR_Z16F) + (size_t)BN * NN * 512
                                          : u16p(dout, SCR_Z16VF);
            const long i = i4 * 4;
            const int d = (int)(i & (DD - 1));
            const long r = i >> 8;
            const int n = (int)(r & (NN - 1));
            const long bc = r >> 11;
            const int c = (int)(bc & 1), b = (int)(bc >> 1);
            float4 v = *(const float4*)&Z[i];
            ushort4 o;
            o.x = (unsigned short)f2bf(v.x); o.y = (unsigned short)f2bf(v.y);
            o.z = (unsigned short)f2bf(v.z); o.w = (unsigned short)f2bf(v.w);
            *(ushort4*)&O[((size_t)(b * NN + n)) * 512 + c * 256 + d] = o;
        }
        // weights -> 6 bf16 mats [d][512]
        for (long e4 = tid; e4 < 196608; e4 += nthr) {
            const long e = e4 * 4;
            const int k = (int)(e & 511);
            const long rest = e >> 9;
            const int dd = (int)(rest & 255);
            const int m = (int)(rest >> 8);
            const float* Ws = (m == 0) ? Wq : (m == 1) ? Wk : (m <= 3) ? Wv : Wp;
            int mode;
            if (m < 3)      { mode = 0; }
            else if (m == 3){ mode = 1; }
            else            { mode = m - 4; }
            const int kc = k >> 8, kk = k & 255;
            int wc; float sgn;
            if (mode == 0) { wc = kc; sgn = kc ? -1.f : 1.f; }
            else           { wc = 1 - kc; sgn = 1.f; }
            float4 v = *(const float4*)&Ws[((size_t)wc * DD + dd) * DD + kk];
            ushort4 o;
            o.x = (unsigned short)f2bf(sgn * v.x); o.y = (unsigned short)f2bf(sgn * v.y);
            o.z = (unsigned short)f2bf(sgn * v.z); o.w = (unsigned short)f2bf(sgn * v.w);
            unsigned short* dst = (m < 4)
                ? u16p(dout, SCR_Z16VF) + U_W16 + (size_t)m * 131072
                : u16p(dout, SCR_W16P) + (size_t)(m - 4) * 131072;
            *(ushort4*)&dst[(size_t)dd * 512 + k] = o;
        }
        // structural fills: VV ch0 ones, VV ch1 zero, UV ch1 zero x4, LH zero
        const float4 ones = {1.f, 1.f, 1.f, 1.f};
        const float4 zz4 = {0.f, 0.f, 0.f, 0.f};
        float* VV0 = dout + OFF_VV;
        for (long u = tid; u < 131072; u += nthr) *(float4*)&VV0[u * 4] = ones;
        float* VV1 = dout + OFF_VV + (size_t)NN * DD;
        for (long u = tid; u < 131072; u += nthr) *(float4*)&VV1[u * 4] = zz4;
        for (int b = 0; b < BN; ++b) {
            float* U1 = dout + OFF_UV + (size_t)(2 * b + 1) * NN * DD;
            for (long u = tid; u < 131072; u += nthr) *(float4*)&U1[u * 4] = zz4;
        }
        float* LH = dout + OFF_LH;
        for (long u = tid; u < 128; u += nthr) *(float4*)&LH[u * 4] = zz4;
        // zero QN/KN/L (24576 floats = 6144 f4)
        for (long u = tid; u < 6144; u += nthr) *(float4*)&dout[SCR_QN + u * 4] = zz4;
        // scalars (block 0)
        if (blockIdx.x == 0) {
            float* red = smemf;  // reuse LDS
            float c2 = lamC[t] * lamC[t];
            float ga = c2 * (lamGa[t] * lamGa[t] + EPSF);
            float om = c2 * (lamOm[t] * lamOm[t] + EPSF);
            for (int o = 32; o > 0; o >>= 1) {
                ga += __shfl_down(ga, o, 64);
                om += __shfl_down(om, o, 64);
            }
            if ((t & 63) == 0) { red[t >> 6] = ga; red[4 + (t >> 6)] = om; }
            __syncthreads();
            if (t == 0) {
                float gs = red[0] + red[1] + red[2] + red[3];
                float os = red[4] + red[5] + red[6] + red[7];
                float* scal = dout + SCR_SC;
                scal[0] = tau[0] * tau[0];
                scal[1] = 1.f / (1.f + __expf(-delta[0]));
                scal[2] = gs / 256.f;
                scal[3] = os / 256.f;
            }
        }
    }
    gbar(dout);

    // ================= P1: QKV projections (512 jobs) =================
    {
        const int job = blockIdx.x;
        const int z = job >> 7;
        const int rem = job & 127;
        const int d0 = (rem & 1) * 128;
        const int by = rem >> 1;
        const int b = by >> 4;
        const int n0 = (by & 15) * 128;

        const unsigned short* Z16 =
            (z == 0) ? u16pc(dout, SCR_Z16F)
          : (z == 1) ? u16pc(dout, SCR_Z16F) + (size_t)BN * NN * 512
                     : u16pc(dout, SCR_Z16VF);
        const unsigned short* W16 = u16pc(dout, SCR_Z16VF) + U_W16 + (size_t)z * 131072;
        const float* bias = (z == 0) ? bq : (z == 1) ? bk : bv;
        const int bofs = (z == 3) ? DD : 0;
        const unsigned short* Abase = Z16 + (size_t)(b * NN + n0) * 512;
        const unsigned short* Bbase = W16 + (size_t)d0 * 512;

        f32x4 acc[4][4];
#pragma unroll
        for (int i = 0; i < 4; ++i)
#pragma unroll
            for (int j = 0; j < 4; ++j) acc[i][j] = (f32x4){0.f, 0.f, 0.f, 0.f};

        for (int kt = 0; kt < 16; ++kt) {
            const int kk0 = kt * 32;
            stage_tile(Abase + kk0, 512, Al, t);
            stage_tile(Bbase + kk0, 512, Bl, t);
            __syncthreads();
            bf16x8 af[4], bff[4];
#pragma unroll
            for (int mi = 0; mi < 4; ++mi) af[mi] = *(const bf16x8*)&Al[(wm + mi * 16 + lm) * 32 + quad * 8];
#pragma unroll
            for (int nj = 0; nj < 4; ++nj) bff[nj] = *(const bf16x8*)&Bl[(wn + nj * 16 + lm) * 32 + quad * 8];
#pragma unroll
            for (int mi = 0; mi < 4; ++mi)
#pragma unroll
                for (int nj = 0; nj < 4; ++nj)
                    acc[mi][nj] = __builtin_amdgcn_mfma_f32_16x16x32_bf16(af[mi], bff[nj], acc[mi][nj], 0, 0, 0);
            __syncthreads();
        }

        if (z <= 1) {
            unsigned short* O16 = u16p(dout, SCR_B0) + (z ? U_K16 : U_Q16) + (size_t)b * NN * DD;
            float* NRM = dout + (z ? SCR_KN : SCR_QN) + b * NN;
#pragma unroll
            for (int mi = 0; mi < 4; ++mi)
#pragma unroll
                for (int r = 0; r < 4; ++r) {
                    const int m = n0 + wm + mi * 16 + quad * 4 + r;
                    float ss = 0.f;
#pragma unroll
                    for (int nj = 0; nj < 4; ++nj) {
                        const int d = d0 + wn + nj * 16 + lm;
                        unsigned short h = (unsigned short)f2bf(acc[mi][nj][r] + bias[d]);
                        O16[(size_t)m * DD + d] = h;
                        const float vb = bf2f(h);
                        ss = fmaf(vb, vb, ss);
                    }
                    ss += __shfl_down(ss, 8, 16); ss += __shfl_down(ss, 4, 16);
                    ss += __shfl_down(ss, 2, 16); ss += __shfl_down(ss, 1, 16);
                    if (lm == 0) atomicAdd(&NRM[m], ss);
                }
        } else if (z == 2) {
            float* UV0 = dout + OFF_UV + (size_t)(b * 2) * NN * DD;
#pragma unroll
            for (int mi = 0; mi < 4; ++mi)
#pragma unroll
                for (int r = 0; r < 4; ++r) {
                    const int m = n0 + wm + mi * 16 + quad * 4 + r;
#pragma unroll
                    for (int nj = 0; nj < 4; ++nj) {
                        const int d = d0 + wn + nj * 16 + lm;
                        UV0[(size_t)m * DD + d] = acc[mi][nj][r] + bias[d];
                    }
                }
        } else {
            const float s1 = 1.f - dout[SCR_SC + 1];
            float* EST1 = dout + OFF_EST + (size_t)(b * 2 + 1) * NN * DD;
            unsigned short* E16 = u16p(dout, SCR_E16F) + (size_t)b * NN * 512;
#pragma unroll
            for (int mi = 0; mi < 4; ++mi)
#pragma unroll
                for (int r = 0; r < 4; ++r) {
                    const int m = n0 + wm + mi * 16 + quad * 4 + r;
#pragma unroll
                    for (int nj = 0; nj < 4; ++nj) {
                        const int d = d0 + wn + nj * 16 + lm;
                        const float v = s1 * (acc[mi][nj][r] + bias[bofs + d]);
                        EST1[(size_t)m * DD + d] = v;
                        E16[(size_t)m * 512 + 256 + d] = (unsigned short)f2bf(v);
                    }
                }
        }
    }
    gbar(dout);

    // ================= P2: V transpose (512 jobs) =================
    {
        float (*T)[65] = (float(*)[65])smemf;
        const int job = blockIdx.x;
        const int b = job >> 7, rem = job & 127;
        const int db = (rem >> 5) * 64, nb = (rem & 31) * 64;
        const float* V = dout + OFF_UV + (size_t)(b * 2) * NN * DD;
        unsigned short* VT = u16p(dout, SCR_B0) + U_VT16 + (size_t)b * DD * NN;
        const int tr = t >> 4, tc = (t & 15) * 4;
#pragma unroll
        for (int p = 0; p < 4; ++p) {
            float4 v = *(const float4*)&V[(size_t)(nb + tr + p * 16) * DD + db + tc];
            T[tr + p * 16][tc + 0] = v.x; T[tr + p * 16][tc + 1] = v.y;
            T[tr + p * 16][tc + 2] = v.z; T[tr + p * 16][tc + 3] = v.w;
        }
        __syncthreads();
#pragma unroll
        for (int p = 0; p < 4; ++p) {
            const int d = tr + p * 16;
            ushort4 o;
            o.x = (unsigned short)f2bf(T[tc + 0][d]);
            o.y = (unsigned short)f2bf(T[tc + 1][d]);
            o.z = (unsigned short)f2bf(T[tc + 2][d]);
            o.w = (unsigned short)f2bf(T[tc + 3][d]);
            *(ushort4*)&VT[(size_t)(db + d) * NN + nb + tc] = o;
        }
        __syncthreads();
    }
    gbar(dout);

    // ================= P3: causal scores (544 jobs) =================
    for (int xj = blockIdx.x; xj < 544; xj += gridDim.x) {
        const int b = xj / 136, x = xj % 136;
        int ti = (int)((sqrtf(8.f * x + 1.f) - 1.f) * 0.5f);
        while ((ti + 1) * (ti + 2) / 2 <= x) ++ti;
        while (ti * (ti + 1) / 2 > x) --ti;
        const int tj = x - ti * (ti + 1) / 2;
        const int i0 = ti * 128, j0 = tj * 128;
        const unsigned short* Q16 = u16pc(dout, SCR_B0) + U_Q16 + (size_t)b * NN * DD;
        const unsigned short* K16 = u16pc(dout, SCR_B0) + U_K16 + (size_t)b * NN * DD;
        const unsigned short* Abase = Q16 + (size_t)i0 * DD;
        const unsigned short* Bbase = K16 + (size_t)j0 * DD;

        f32x4 acc[4][4];
#pragma unroll
        for (int i = 0; i < 4; ++i)
#pragma unroll
            for (int j = 0; j < 4; ++j) acc[i][j] = (f32x4){0.f, 0.f, 0.f, 0.f};

        for (int kt = 0; kt < 8; ++kt) {
            const int kk0 = kt * 32;
            stage_tile(Abase + kk0, DD, Al, t);
            stage_tile(Bbase + kk0, DD, Bl, t);
            __syncthreads();
            bf16x8 af[4], bff[4];
#pragma unroll
            for (int mi = 0; mi < 4; ++mi) af[mi] = *(const bf16x8*)&Al[(wm + mi * 16 + lm) * 32 + quad * 8];
#pragma unroll
            for (int nj = 0; nj < 4; ++nj) bff[nj] = *(const bf16x8*)&Bl[(wn + nj * 16 + lm) * 32 + quad * 8];
#pragma unroll
            for (int mi = 0; mi < 4; ++mi)
#pragma unroll
                for (int nj = 0; nj < 4; ++nj)
                    acc[mi][nj] = __builtin_amdgcn_mfma_f32_16x16x32_bf16(af[mi], bff[nj], acc[mi][nj], 0, 0, 0);
            __syncthreads();
        }

        const float tau2 = dout[SCR_SC + 0], ga = dout[SCR_SC + 2], om = dout[SCR_SC + 3];
        unsigned short* WT = w16p(dout, b) + (size_t)x * 16384;
        const float* QN_ = dout + SCR_QN + b * NN;
        const float* KN_ = dout + SCR_KN + b * NN;
        float kn[4], tjv[4]; int jj[4];
#pragma unroll
        for (int nj = 0; nj < 4; ++nj) {
            jj[nj] = j0 + wn + nj * 16 + lm;
            kn[nj] = KN_[jj[nj]];
            tjv[nj] = tmeas[jj[nj]];
        }
#pragma unroll
        for (int mi = 0; mi < 4; ++mi)
#pragma unroll
            for (int r = 0; r < 4; ++r) {
                const int li = wm + mi * 16 + quad * 4 + r;
                const int i = i0 + li;
                const float qni = QN_[i], tqi = tmeas[i];
                float rs = 0.f;
#pragma unroll
                for (int nj = 0; nj < 4; ++nj) {
                    float xx = ga + om * fabsf(tqi - tjv[nj]) + qni + kn[nj] - 2.f * acc[mi][nj][r];
                    xx = fmaxf(xx, 1e-30f);
                    float w = (tau2 == 1.f) ? __builtin_amdgcn_rcpf(xx)
                                            : __expf(-tau2 * __logf(xx));
                    if (jj[nj] > i) w = 0.f;
                    const unsigned short h = (unsigned short)f2bf(w);
                    WT[(size_t)li * 128 + (wn + nj * 16 + lm)] = h;
                    rs += bf2f(h);
                }
                rs += __shfl_down(rs, 8, 16); rs += __shfl_down(rs, 4, 16);
                rs += __shfl_down(rs, 2, 16); rs += __shfl_down(rs, 1, 16);
                if (lm == 0) atomicAdd(&dout[SCR_L + b * NN + i], rs);
            }
    }
    gbar(dout);

    // ================= P4: est_inner GEMM (240 jobs) =================
    for (int job = blockIdx.x; job < 240; job += gridDim.x) {
        const int b = job / 60, xx = job % 60;
        const int chunk = xx >> 1, half = xx & 1;
        int y = chunk, TI = 0, cb = 0;
        for (;;) { const int nc = nc_of(TI); if (y < nc) break; y -= nc; cb += nc; ++TI; }
        const int kbeg = y * 768;
        const int kend = min(kbeg + 768, (TI + 1) * 128);
        const int nst = (kend - kbeg) >> 5;
        const int cidx = cb + y;
        const int tri = TI * (TI + 1) / 2;
        const unsigned short* WT = w16pc(dout, b);
        const unsigned short* VT = u16pc(dout, SCR_B0) + U_VT16 + (size_t)b * DD * NN
                                 + (size_t)(half * 128) * NN;

        f32x4 acc[4][4];
#pragma unroll
        for (int i = 0; i < 4; ++i)
#pragma unroll
            for (int j = 0; j < 4; ++j) acc[i][j] = (f32x4){0.f, 0.f, 0.f, 0.f};

        for (int kt = 0; kt < nst; ++kt) {
            const int kk0 = kbeg + kt * 32;
            const int tile = kk0 >> 7;
            stage_tile(WT + (size_t)(tri + tile) * 16384 + (kk0 & 127), 128, Al, t);
            stage_tile(VT + kk0, NN, Bl, t);
            __syncthreads();
            bf16x8 af[4], bff[4];
#pragma unroll
            for (int mi = 0; mi < 4; ++mi) af[mi] = *(const bf16x8*)&Al[(wm + mi * 16 + lm) * 32 + quad * 8];
#pragma unroll
            for (int nj = 0; nj < 4; ++nj) bff[nj] = *(const bf16x8*)&Bl[(wn + nj * 16 + lm) * 32 + quad * 8];
#pragma unroll
            for (int mi = 0; mi < 4; ++mi)
#pragma unroll
                for (int nj = 0; nj < 4; ++nj)
                    acc[mi][nj] = __builtin_amdgcn_mfma_f32_16x16x32_bf16(af[mi], bff[nj], acc[mi][nj], 0, 0, 0);
            __syncthreads();
        }
        unsigned short* P = u16p(dout, SCR_E16F) + U_PART +
                            ((size_t)(b * 30 + cidx)) * 128 * 256;
#pragma unroll
        for (int mi = 0; mi < 4; ++mi)
#pragma unroll
            for (int r = 0; r < 4; ++r) {
                const int ri = wm + mi * 16 + quad * 4 + r;
#pragma unroll
                for (int nj = 0; nj < 4; ++nj) {
                    const int d = half * 128 + wn + nj * 16 + lm;
                    P[(size_t)ri * 256 + d] = (unsigned short)f2bf(acc[mi][nj][r]);
                }
            }
    }
    gbar(dout);

    // ================= P5: blend (2048) + Qij rows (8192) =================
    for (int job = blockIdx.x; job < 10240; job += gridDim.x) {
        if (job < 2048) {
            const int b = job >> 9, x = job & 511;
            const int i = x * 4 + (t >> 6);
            const int d4 = (t & 63) * 4;
            const int TI = i >> 7;
            const int nc = nc_of(TI), cb = cb_of(TI);
            const float s = dout[SCR_SC + 1];
            const float linv = 1.f / dout[SCR_L + b * NN + i];
            const unsigned short* P = u16pc(dout, SCR_E16F) + U_PART;
            float4 sum = {0.f, 0.f, 0.f, 0.f};
            for (int c = 0; c < nc; ++c) {
                ushort4 pv = *(const ushort4*)&P[((size_t)(b * 30 + cb + c) * 128 + (i & 127)) * 256 + d4];
                sum.x += bf2f(pv.x); sum.y += bf2f(pv.y);
                sum.z += bf2f(pv.z); sum.w += bf2f(pv.w);
            }
            const float4 vr = *(const float4*)&dout[OFF_UV + ((size_t)(b * 2) * NN + i) * DD + d4];
            const float sl = s * linv;
            float4 ev;
            ev.x = (1.f - s) * vr.x + sl * sum.x;
            ev.y = (1.f - s) * vr.y + sl * sum.y;
            ev.z = (1.f - s) * vr.z + sl * sum.z;
            ev.w = (1.f - s) * vr.w + sl * sum.w;
            *(float4*)&dout[OFF_EST + ((size_t)(b * 2) * NN + i) * DD + d4] = ev;
            ushort4 o;
            o.x = (unsigned short)f2bf(ev.x); o.y = (unsigned short)f2bf(ev.y);
            o.z = (unsigned short)f2bf(ev.z); o.w = (unsigned short)f2bf(ev.w);
            *(ushort4*)&u16p(dout, SCR_E16F)[((size_t)(b * NN + i)) * 512 + d4] = o;
        } else {
            const int jj = job - 2048;
            const int b = jj >> 11, i = jj & 2047;
            const int TI = i >> 7, li = i & 127;
            const int tri = TI * (TI + 1) / 2;
            const float linv = 1.f / dout[SCR_L + b * NN + i];
            const unsigned short* WTb = w16pc(dout, b);
            float* row = dout + OFF_QIJ + (size_t)b * 2 * NN * NN + (size_t)i * NN;
            for (int j4 = t * 4; j4 < NN; j4 += 1024) {
                const int tj = j4 >> 7;
                float4 o = {0.f, 0.f, 0.f, 0.f};
                if (tj <= TI) {
                    ushort4 h = *(const ushort4*)&WTb[((size_t)(tri + tj)) * 16384
                                                      + (size_t)li * 128 + (j4 & 127)];
                    o.x = bf2f(h.x) * linv; o.y = bf2f(h.y) * linv;
                    o.z = bf2f(h.z) * linv; o.w = bf2f(h.w) * linv;
                }
                *(float4*)&row[j4] = o;
            }
        }
    }
    gbar(dout);

    // ====== P6: output projection (256 jobs) + zero b2/b3-imag (256 blks) ======
    {
        const int job = blockIdx.x;
        if (job < 256) {
            const int z = job >> 7;
            const int rem = job & 127;
            const int d0 = (rem & 1) * 128;
            const int by = rem >> 1;
            const int b = by >> 4;
            const int n0 = (by & 15) * 128;
            const unsigned short* E16 = u16pc(dout, SCR_E16F) + (size_t)b * NN * 512;
            const unsigned short* W16 = u16pc(dout, SCR_W16P) + (size_t)z * 131072;
            const unsigned short* Abase = E16 + (size_t)n0 * 512;
            const unsigned short* Bbase = W16 + (size_t)d0 * 512;

            f32x4 acc[4][4];
#pragma unroll
            for (int i = 0; i < 4; ++i)
#pragma unroll
                for (int j = 0; j < 4; ++j) acc[i][j] = (f32x4){0.f, 0.f, 0.f, 0.f};

            for (int kt = 0; kt < 16; ++kt) {
                const int kk0 = kt * 32;
                stage_tile(Abase + kk0, 512, Al, t);
                stage_tile(Bbase + kk0, 512, Bl, t);
                __syncthreads();
                bf16x8 af[4], bff[4];
#pragma unroll
                for (int mi = 0; mi < 4; ++mi) af[mi] = *(const bf16x8*)&Al[(wm + mi * 16 + lm) * 32 + quad * 8];
#pragma unroll
                for (int nj = 0; nj < 4; ++nj) bff[nj] = *(const bf16x8*)&Bl[(wn + nj * 16 + lm) * 32 + quad * 8];
#pragma unroll
                for (int mi = 0; mi < 4; ++mi)
#pragma unroll
                    for (int nj = 0; nj < 4; ++nj)
                        acc[mi][nj] = __builtin_amdgcn_mfma_f32_16x16x32_bf16(af[mi], bff[nj], acc[mi][nj], 0, 0, 0);
                __syncthreads();
            }
            const int bofs = z ? DD : 0;
            float* O = dout + OFF_OUT + (size_t)(b * 2 + z) * NN * DD;
#pragma unroll
            for (int mi = 0; mi < 4; ++mi)
#pragma unroll
                for (int r = 0; r < 4; ++r) {
                    const int m = n0 + wm + mi * 16 + quad * 4 + r;
#pragma unroll
                    for (int nj = 0; nj < 4; ++nj) {
                        const int d = d0 + wn + nj * 16 + lm;
                        O[(size_t)m * DD + d] = acc[mi][nj][r] + bp[bofs + d];
                    }
                }
        } else {
            // zero b2-imag + b3-imag (w16 scratch; dead after P5)
            const long jb = job - 256;
            const float4 zz4 = {0.f, 0.f, 0.f, 0.f};
            for (long u = jb * 256 + t; u < (long)NN * NN / 4; u += 256L * 256) {
                *(float4*)&dout[SCR_Z16F + u * 4] = zz4;
                *(float4*)&dout[SCR_Z16VF + u * 4] = zz4;
            }
        }
    }
    gbar(dout);

    // ================= P7: zero b0-imag + b1-imag (incl. barrier words) =====
    {
        const long tid = (long)blockIdx.x * 256 + t;
        const long nthr = (long)gridDim.x * 256;
        const float4 zz4 = {0.f, 0.f, 0.f, 0.f};
        for (long u = tid; u < (long)NN * NN / 4; u += nthr) {
            *(float4*)&dout[SCR_B0 + u * 4] = zz4;
            *(float4*)&dout[SCR_E16F + u * 4] = zz4;
        }
    }
}

extern "C" void kernel_launch(void* const* d_in, const int* in_sizes, int n_in,
                              void* d_out, int out_size, void* d_ws, size_t ws_size,
                              hipStream_t stream) {
    const float* Zq = (const float*)d_in[0];
    const float* Zk = (const float*)d_in[1];
    const float* Zv = (const float*)d_in[2];
    const float* tm = (const float*)d_in[3];
    const float* Wq = (const float*)d_in[4];
    const float* bq = (const float*)d_in[5];
    const float* Wk = (const float*)d_in[6];
    const float* bk = (const float*)d_in[7];
    const float* Wv = (const float*)d_in[8];
    const float* bv = (const float*)d_in[9];
    const float* Wp = (const float*)d_in[10];
    const float* bp = (const float*)d_in[11];
    const float* lamOm = (const float*)d_in[13];
    const float* lamGa = (const float*)d_in[14];
    const float* tau = (const float*)d_in[15];
    const float* delta = (const float*)d_in[16];
    const float* lamC = (const float*)d_in[17];
    float* out = (float*)d_out;

    // zero the grid-barrier words (output buffer is poisoned pre-launch)
    hipMemsetAsync((void*)(out + SCR_SC + 8), 0, 8, stream);
    k_mega<<<dim3(NBLK), dim3(256), 0, stream>>>(
        Zq, Zk, Zv, tm, Wq, bq, Wk, bk, Wv, bv, Wp, bp,
        lamOm, lamGa, tau, delta, lamC, out);
}

// Round 6
// 347.272 us; speedup vs baseline: 3.2245x; 1.9876x over previous
//
#include <hip/hip_runtime.h>
#include <math.h>

#define BN 4
#define NN 2048
#define DD 256
#define EPSF 1e-5f

typedef __attribute__((ext_vector_type(8))) short bf16x8;
typedef __attribute__((ext_vector_type(4))) float f32x4;

// ---- output layout (float offsets) ----
constexpr size_t OFF_EST = 0;                                  // (B,2,N,D)
constexpr size_t OFF_OUT = (size_t)BN * 2 * NN * DD;           // (B,2,N,D)
constexpr size_t OFF_QIJ = OFF_OUT + (size_t)BN * 2 * NN * DD; // (B,2,N,N)
constexpr size_t OFF_VV  = OFF_QIJ + (size_t)BN * 2 * NN * NN; // (1,2,N,D)
constexpr size_t OFF_UV  = OFF_VV + (size_t)2 * NN * DD;       // (B,2,N,D)
constexpr size_t OFF_LH  = OFF_UV + (size_t)BN * 2 * NN * DD;  // (2,D,1)

// ---- scratch regions (Q_ij imaginary channels; zeroed before return) ----
constexpr size_t SCR_B0   = OFF_QIJ + (size_t)NN * NN;
constexpr size_t U_Q16    = 0;
constexpr size_t U_K16    = (size_t)BN * NN * DD;
constexpr size_t U_VT16   = 2 * (size_t)BN * NN * DD;
constexpr size_t SCR_QN   = SCR_B0 + 3 * (size_t)BN * NN * DD / 2;
constexpr size_t SCR_KN   = SCR_QN + (size_t)BN * NN;
constexpr size_t SCR_L    = SCR_KN + (size_t)BN * NN;
constexpr size_t SCR_SC   = SCR_L + (size_t)BN * NN;   // [tau2, s, ga_bar, om_bar]
constexpr size_t SCR_W16P = SCR_SC + 16;
constexpr size_t SCR_E16F = OFF_QIJ + 3 * (size_t)NN * NN;
constexpr size_t U_PART   = (size_t)BN * NN * 512;
constexpr size_t SCR_Z16F = OFF_QIJ + 5 * (size_t)NN * NN;
constexpr size_t SCR_Z16VF = OFF_QIJ + 7 * (size_t)NN * NN;
constexpr size_t U_W16    = (size_t)BN * NN * 512;
constexpr size_t W16_PER_B = 136 * 16384;

__device__ __forceinline__ short f2bf(float x) {
    union { float f; unsigned u; } v; v.f = x;
    unsigned r = v.u + 0x7fff + ((v.u >> 16) & 1);
    return (short)(r >> 16);
}
__device__ __forceinline__ float bf2f(unsigned short h) {
    union { unsigned u; float f; } v; v.u = ((unsigned)h) << 16;
    return v.f;
}
__device__ __forceinline__ unsigned short* u16p(float* d, size_t fofs) {
    return (unsigned short*)(d + fofs);
}
__device__ __forceinline__ const unsigned short* u16pc(const float* d, size_t fofs) {
    return (const unsigned short*)(d + fofs);
}
__device__ __forceinline__ unsigned short* w16p(float* d, int b) {
    return (b < 3) ? u16p(d, SCR_Z16F) + (size_t)b * W16_PER_B
                   : u16p(d, SCR_Z16VF);
}
__device__ __forceinline__ const unsigned short* w16pc(const float* d, int b) {
    return (b < 3) ? u16pc(d, SCR_Z16F) + (size_t)b * W16_PER_B
                   : u16pc(d, SCR_Z16VF);
}
__device__ __forceinline__ int nc_of(int TI) { return TI >= 12 ? 3 : (TI >= 6 ? 2 : 1); }
__device__ __forceinline__ int cb_of(int TI) {
    return TI < 6 ? TI : (TI < 12 ? 6 + 2 * (TI - 6) : 18 + 3 * (TI - 12));
}

// async global->LDS, 16B per lane (m97 pattern)
__device__ __forceinline__ void gll16(const unsigned short* g, short* l) {
    __builtin_amdgcn_global_load_lds(
        (const __attribute__((address_space(1))) unsigned*)g,
        (__attribute__((address_space(3))) unsigned*)l, 16, 0, 0);
}
// stage a 128x32 bf16 tile into ldsbuf[128*32] (linear); 2 issues/wave
__device__ __forceinline__ void stage_tile(const unsigned short* gbase, size_t stride_sh,
                                           short* ldsbuf, int t) {
    const int w = t >> 6, L = t & 63;
#pragma unroll
    for (int p = 0; p < 2; ++p) {
        const int r0 = w * 32 + p * 16;
        const unsigned short* src = gbase + (size_t)(r0 + (L >> 2)) * stride_sh + (L & 3) * 8;
        gll16(src, ldsbuf + r0 * 32);
    }
}
// stage a 64x32 bf16 tile into ldsbuf[64*32]; 1 issue/wave
__device__ __forceinline__ void stage64(const unsigned short* gbase, size_t stride_sh,
                                        short* ldsbuf, int t) {
    const int w = t >> 6, L = t & 63;
    const int r0 = w * 16;
    const unsigned short* src = gbase + (size_t)(r0 + (L >> 2)) * stride_sh + (L & 3) * 8;
    gll16(src, ldsbuf + r0 * 32);
}

// =====================================================================
// cvt (+ fused prep): z 0..2 = Z tensors -> bf16 [b][n][512]
// z=3: weights -> 6 bf16 mats [d][512]; z=4: scalars + zero QN/KN/L
// =====================================================================
__global__ void k_cvt(const float* __restrict__ Zq, const float* __restrict__ Zk,
                      const float* __restrict__ Zv,
                      const float* __restrict__ Wq, const float* __restrict__ Wk,
                      const float* __restrict__ Wv, const float* __restrict__ Wp,
                      const float* __restrict__ tau, const float* __restrict__ delta,
                      const float* __restrict__ lamOm, const float* __restrict__ lamGa,
                      const float* __restrict__ lamC,
                      float* __restrict__ dout) {
    const int z = blockIdx.z;
    if (z < 3) {
        const float* Z = (z == 0) ? Zq : (z == 1) ? Zk : Zv;
        unsigned short* O = (z == 0) ? u16p(dout, SCR_Z16F)
                          : (z == 1) ? u16p(dout, SCR_Z16F) + (size_t)BN * NN * 512
                                     : u16p(dout, SCR_Z16VF);
        const long n4 = (long)BN * 2 * NN * DD / 4;
        for (long i4 = (long)blockIdx.x * 256 + threadIdx.x; i4 < n4;
             i4 += (long)gridDim.x * 256) {
            const long i = i4 * 4;
            const int d = (int)(i & (DD - 1));
            const long r = i >> 8;
            const int n = (int)(r & (NN - 1));
            const long bc = r >> 11;
            const int c = (int)(bc & 1), b = (int)(bc >> 1);
            float4 v = *(const float4*)&Z[i];
            ushort4 o;
            o.x = (unsigned short)f2bf(v.x); o.y = (unsigned short)f2bf(v.y);
            o.z = (unsigned short)f2bf(v.z); o.w = (unsigned short)f2bf(v.w);
            *(ushort4*)&O[((size_t)(b * NN + n)) * 512 + c * 256 + d] = o;
        }
    } else if (z == 3) {
        const float* Ws[4] = {Wq, Wk, Wv, Wp};
        const long n4 = 6L * 256 * 512 / 4;
        for (long e4 = (long)blockIdx.x * 256 + threadIdx.x; e4 < n4;
             e4 += (long)gridDim.x * 256) {
            const long e = e4 * 4;
            const int k = (int)(e & 511);
            const long rest = e >> 9;
            const int dd = (int)(rest & 255);
            const int m = (int)(rest >> 8);
            int proj, mode;
            if (m < 3)      { proj = m; mode = 0; }
            else if (m == 3){ proj = 2; mode = 1; }
            else            { proj = 3; mode = m - 4; }
            const int kc = k >> 8, kk = k & 255;
            int wc; float sgn;
            if (mode == 0) { wc = kc; sgn = kc ? -1.f : 1.f; }
            else           { wc = 1 - kc; sgn = 1.f; }
            float4 v = *(const float4*)&Ws[proj][((size_t)wc * DD + dd) * DD + kk];
            ushort4 o;
            o.x = (unsigned short)f2bf(sgn * v.x); o.y = (unsigned short)f2bf(sgn * v.y);
            o.z = (unsigned short)f2bf(sgn * v.z); o.w = (unsigned short)f2bf(sgn * v.w);
            unsigned short* dst = (m < 4)
                ? u16p(dout, SCR_Z16VF) + U_W16 + (size_t)m * 131072
                : u16p(dout, SCR_W16P) + (size_t)(m - 4) * 131072;
            *(ushort4*)&dst[(size_t)dd * 512 + k] = o;
        }
    } else {
        const int idx = blockIdx.x * 256 + threadIdx.x;
        if (idx < 3 * BN * NN) dout[SCR_QN + idx] = 0.f;
        if (blockIdx.x == 0) {
            __shared__ float red[8];
            const int t = threadIdx.x;
            float c2 = lamC[t] * lamC[t];
            float ga = c2 * (lamGa[t] * lamGa[t] + EPSF);
            float om = c2 * (lamOm[t] * lamOm[t] + EPSF);
            for (int o = 32; o > 0; o >>= 1) {
                ga += __shfl_down(ga, o, 64);
                om += __shfl_down(om, o, 64);
            }
            if ((t & 63) == 0) { red[t >> 6] = ga; red[4 + (t >> 6)] = om; }
            __syncthreads();
            if (t == 0) {
                float gs = red[0] + red[1] + red[2] + red[3];
                float os = red[4] + red[5] + red[6] + red[7];
                float* scal = dout + SCR_SC;
                scal[0] = tau[0] * tau[0];
                scal[1] = 1.f / (1.f + __expf(-delta[0]));
                scal[2] = gs / 256.f;
                scal[3] = os / 256.f;
            }
        }
    }
}

// =====================================================================
// QKV projection, 64x128 tiles (acc[2][4]) -> 1024 blocks, 4 blk/CU
// z: 0=Qr->Q16(+QN), 1=Kr->K16(+KN), 2=Vr->UVch0, 3=Vi->est ch1 + E16 ch1
// =====================================================================
__global__ __launch_bounds__(256) void k_qkv(const float* __restrict__ bq,
                                             const float* __restrict__ bk,
                                             const float* __restrict__ bv,
                                             float* __restrict__ dout)
{
    __shared__ short Al[64 * 32];
    __shared__ short Bl[128 * 32];
    const int z = blockIdx.z;
    const int d0 = blockIdx.x * 128;
    const int b = blockIdx.y >> 5;
    const int n0 = (blockIdx.y & 31) * 64;

    const unsigned short* Z16 =
        (z == 0) ? u16pc(dout, SCR_Z16F)
      : (z == 1) ? u16pc(dout, SCR_Z16F) + (size_t)BN * NN * 512
                 : u16pc(dout, SCR_Z16VF);
    const unsigned short* W16 = u16pc(dout, SCR_Z16VF) + U_W16 + (size_t)z * 131072;
    const float* bias = (z == 0) ? bq : (z == 1) ? bk : bv;
    const int bofs = (z == 3) ? DD : 0;

    const int t = threadIdx.x, wave = t >> 6, lane = t & 63, quad = lane >> 4, lm = lane & 15;
    const int wr = (wave >> 1) * 32, wc = (wave & 1) * 64;
    const unsigned short* Abase = Z16 + (size_t)(b * NN + n0) * 512;
    const unsigned short* Bbase = W16 + (size_t)d0 * 512;

    f32x4 acc[2][4];
#pragma unroll
    for (int i = 0; i < 2; ++i)
#pragma unroll
        for (int j = 0; j < 4; ++j) acc[i][j] = (f32x4){0.f, 0.f, 0.f, 0.f};

    for (int kt = 0; kt < 16; ++kt) {
        const int kk0 = kt * 32;
        stage64(Abase + kk0, 512, Al, t);
        stage_tile(Bbase + kk0, 512, Bl, t);
        __syncthreads();
        bf16x8 af[2], bff[4];
#pragma unroll
        for (int mi = 0; mi < 2; ++mi) af[mi] = *(const bf16x8*)&Al[(wr + mi * 16 + lm) * 32 + quad * 8];
#pragma unroll
        for (int nj = 0; nj < 4; ++nj) bff[nj] = *(const bf16x8*)&Bl[(wc + nj * 16 + lm) * 32 + quad * 8];
#pragma unroll
        for (int mi = 0; mi < 2; ++mi)
#pragma unroll
            for (int nj = 0; nj < 4; ++nj)
                acc[mi][nj] = __builtin_amdgcn_mfma_f32_16x16x32_bf16(af[mi], bff[nj], acc[mi][nj], 0, 0, 0);
        __syncthreads();
    }

    if (z <= 1) {
        unsigned short* O16 = u16p(dout, SCR_B0) + (z ? U_K16 : U_Q16) + (size_t)b * NN * DD;
        float* NRM = dout + (z ? SCR_KN : SCR_QN) + b * NN;
#pragma unroll
        for (int mi = 0; mi < 2; ++mi)
#pragma unroll
            for (int r = 0; r < 4; ++r) {
                const int m = n0 + wr + mi * 16 + quad * 4 + r;
                float ss = 0.f;
#pragma unroll
                for (int nj = 0; nj < 4; ++nj) {
                    const int d = d0 + wc + nj * 16 + lm;
                    unsigned short h = (unsigned short)f2bf(acc[mi][nj][r] + bias[d]);
                    O16[(size_t)m * DD + d] = h;
                    const float vb = bf2f(h);
                    ss = fmaf(vb, vb, ss);
                }
                ss += __shfl_down(ss, 8, 16); ss += __shfl_down(ss, 4, 16);
                ss += __shfl_down(ss, 2, 16); ss += __shfl_down(ss, 1, 16);
                if (lm == 0) atomicAdd(&NRM[m], ss);
            }
    } else if (z == 2) {
        float* UV0 = dout + OFF_UV + (size_t)(b * 2) * NN * DD;
#pragma unroll
        for (int mi = 0; mi < 2; ++mi)
#pragma unroll
            for (int r = 0; r < 4; ++r) {
                const int m = n0 + wr + mi * 16 + quad * 4 + r;
#pragma unroll
                for (int nj = 0; nj < 4; ++nj) {
                    const int d = d0 + wc + nj * 16 + lm;
                    UV0[(size_t)m * DD + d] = acc[mi][nj][r] + bias[d];
                }
            }
    } else {
        const float s1 = 1.f - dout[SCR_SC + 1];
        float* EST1 = dout + OFF_EST + (size_t)(b * 2 + 1) * NN * DD;
        unsigned short* E16 = u16p(dout, SCR_E16F) + (size_t)b * NN * 512;
#pragma unroll
        for (int mi = 0; mi < 2; ++mi)
#pragma unroll
            for (int r = 0; r < 4; ++r) {
                const int m = n0 + wr + mi * 16 + quad * 4 + r;
#pragma unroll
                for (int nj = 0; nj < 4; ++nj) {
                    const int d = d0 + wc + nj * 16 + lm;
                    const float v = s1 * (acc[mi][nj][r] + bias[bofs + d]);
                    EST1[(size_t)m * DD + d] = v;
                    E16[(size_t)m * 512 + 256 + d] = (unsigned short)f2bf(v);
                }
            }
    }
}

// =====================================================================
// output projection, 64x128 tiles -> 1024 blocks
// =====================================================================
__global__ __launch_bounds__(256) void k_outproj(const float* __restrict__ bp,
                                                 float* __restrict__ dout)
{
    __shared__ short Al[64 * 32];
    __shared__ short Bl[128 * 32];
    const int z = blockIdx.z;
    const int d0 = blockIdx.x * 128;
    const int b = blockIdx.y >> 5;
    const int n0 = (blockIdx.y & 31) * 64;
    const unsigned short* E16 = u16pc(dout, SCR_E16F) + (size_t)b * NN * 512;
    const unsigned short* W16 = u16pc(dout, SCR_W16P) + (size_t)z * 131072;

    const int t = threadIdx.x, wave = t >> 6, lane = t & 63, quad = lane >> 4, lm = lane & 15;
    const int wr = (wave >> 1) * 32, wc = (wave & 1) * 64;
    const unsigned short* Abase = E16 + (size_t)n0 * 512;
    const unsigned short* Bbase = W16 + (size_t)d0 * 512;

    f32x4 acc[2][4];
#pragma unroll
    for (int i = 0; i < 2; ++i)
#pragma unroll
        for (int j = 0; j < 4; ++j) acc[i][j] = (f32x4){0.f, 0.f, 0.f, 0.f};

    for (int kt = 0; kt < 16; ++kt) {
        const int kk0 = kt * 32;
        stage64(Abase + kk0, 512, Al, t);
        stage_tile(Bbase + kk0, 512, Bl, t);
        __syncthreads();
        bf16x8 af[2], bff[4];
#pragma unroll
        for (int mi = 0; mi < 2; ++mi) af[mi] = *(const bf16x8*)&Al[(wr + mi * 16 + lm) * 32 + quad * 8];
#pragma unroll
        for (int nj = 0; nj < 4; ++nj) bff[nj] = *(const bf16x8*)&Bl[(wc + nj * 16 + lm) * 32 + quad * 8];
#pragma unroll
        for (int mi = 0; mi < 2; ++mi)
#pragma unroll
            for (int nj = 0; nj < 4; ++nj)
                acc[mi][nj] = __builtin_amdgcn_mfma_f32_16x16x32_bf16(af[mi], bff[nj], acc[mi][nj], 0, 0, 0);
        __syncthreads();
    }
    const int bofs = z ? DD : 0;
    float* O = dout + OFF_OUT + (size_t)(b * 2 + z) * NN * DD;
#pragma unroll
    for (int mi = 0; mi < 2; ++mi)
#pragma unroll
        for (int r = 0; r < 4; ++r) {
            const int m = n0 + wr + mi * 16 + quad * 4 + r;
#pragma unroll
            for (int nj = 0; nj < 4; ++nj) {
                const int d = d0 + wc + nj * 16 + lm;
                O[(size_t)m * DD + d] = acc[mi][nj][r] + bp[bofs + d];
            }
        }
}

// =====================================================================
// transpose V: UV ch0 [b][n][d] fp32 -> VT16 [b][d][n] bf16
// =====================================================================
__global__ void k_vtrans(float* __restrict__ dout) {
    __shared__ float T[64][65];
    const int b = blockIdx.z;
    const int nb = blockIdx.x * 64, db = blockIdx.y * 64;
    const float* V = dout + OFF_UV + (size_t)(b * 2) * NN * DD;
    unsigned short* VT = u16p(dout, SCR_B0) + U_VT16 + (size_t)b * DD * NN;
    const int tr = threadIdx.x >> 4, tc = (threadIdx.x & 15) * 4;
#pragma unroll
    for (int p = 0; p < 4; ++p) {
        float4 v = *(const float4*)&V[(size_t)(nb + tr + p * 16) * DD + db + tc];
        T[tr + p * 16][tc + 0] = v.x; T[tr + p * 16][tc + 1] = v.y;
        T[tr + p * 16][tc + 2] = v.z; T[tr + p * 16][tc + 3] = v.w;
    }
    __syncthreads();
#pragma unroll
    for (int p = 0; p < 4; ++p) {
        const int d = tr + p * 16;
        ushort4 o;
        o.x = (unsigned short)f2bf(T[tc + 0][d]);
        o.y = (unsigned short)f2bf(T[tc + 1][d]);
        o.z = (unsigned short)f2bf(T[tc + 2][d]);
        o.w = (unsigned short)f2bf(T[tc + 3][d]);
        *(ushort4*)&VT[(size_t)(db + d) * NN + nb + tc] = o;
    }
}

// =====================================================================
// causal scores, 64x128 i-half tiles -> 1088 blocks
// w (unnormalized) -> bf16 w16 tile-packed; rounded row sums -> L
// =====================================================================
__global__ __launch_bounds__(256) void k_scores(const float* __restrict__ tmeas,
                                                float* __restrict__ dout) {
    __shared__ short Al[64 * 32];
    __shared__ short Bl[128 * 32];
    const int b = blockIdx.y, x2 = blockIdx.x;
    const int x = x2 >> 1, ih = x2 & 1;
    int ti = (int)((sqrtf(8.f * x + 1.f) - 1.f) * 0.5f);
    while ((ti + 1) * (ti + 2) / 2 <= x) ++ti;
    while (ti * (ti + 1) / 2 > x) --ti;
    const int tj = x - ti * (ti + 1) / 2;
    const int i0 = ti * 128, j0 = tj * 128;
    const int ib = i0 + ih * 64;
    const unsigned short* Q16 = u16pc(dout, SCR_B0) + U_Q16 + (size_t)b * NN * DD;
    const unsigned short* K16 = u16pc(dout, SCR_B0) + U_K16 + (size_t)b * NN * DD;
    const int t = threadIdx.x, wave = t >> 6, lane = t & 63, quad = lane >> 4, lm = lane & 15;
    const int wr = (wave >> 1) * 32, wc = (wave & 1) * 64;
    const unsigned short* Abase = Q16 + (size_t)ib * DD;
    const unsigned short* Bbase = K16 + (size_t)j0 * DD;

    f32x4 acc[2][4];
#pragma unroll
    for (int i = 0; i < 2; ++i)
#pragma unroll
        for (int j = 0; j < 4; ++j) acc[i][j] = (f32x4){0.f, 0.f, 0.f, 0.f};

    for (int kt = 0; kt < 8; ++kt) {
        const int kk0 = kt * 32;
        stage64(Abase + kk0, DD, Al, t);
        stage_tile(Bbase + kk0, DD, Bl, t);
        __syncthreads();
        bf16x8 af[2], bff[4];
#pragma unroll
        for (int mi = 0; mi < 2; ++mi) af[mi] = *(const bf16x8*)&Al[(wr + mi * 16 + lm) * 32 + quad * 8];
#pragma unroll
        for (int nj = 0; nj < 4; ++nj) bff[nj] = *(const bf16x8*)&Bl[(wc + nj * 16 + lm) * 32 + quad * 8];
#pragma unroll
        for (int mi = 0; mi < 2; ++mi)
#pragma unroll
            for (int nj = 0; nj < 4; ++nj)
                acc[mi][nj] = __builtin_amdgcn_mfma_f32_16x16x32_bf16(af[mi], bff[nj], acc[mi][nj], 0, 0, 0);
        __syncthreads();
    }

    const float tau2 = dout[SCR_SC + 0], ga = dout[SCR_SC + 2], om = dout[SCR_SC + 3];
    unsigned short* WT = w16p(dout, b) + (size_t)x * 16384;
    const float* QN_ = dout + SCR_QN + b * NN;
    const float* KN_ = dout + SCR_KN + b * NN;
    float kn[4], tjv[4]; int jj[4], jl[4];
#pragma unroll
    for (int nj = 0; nj < 4; ++nj) {
        jl[nj] = wc + nj * 16 + lm;
        jj[nj] = j0 + jl[nj];
        kn[nj] = KN_[jj[nj]];
        tjv[nj] = tmeas[jj[nj]];
    }
#pragma unroll
    for (int mi = 0; mi < 2; ++mi)
#pragma unroll
        for (int r = 0; r < 4; ++r) {
            const int li = ih * 64 + wr + mi * 16 + quad * 4 + r;
            const int i = i0 + li;
            const float qni = QN_[i], tqi = tmeas[i];
            float rs = 0.f;
#pragma unroll
            for (int nj = 0; nj < 4; ++nj) {
                float xx = ga + om * fabsf(tqi - tjv[nj]) + qni + kn[nj] - 2.f * acc[mi][nj][r];
                xx = fmaxf(xx, 1e-30f);
                float w = (tau2 == 1.f) ? __builtin_amdgcn_rcpf(xx)
                                        : __expf(-tau2 * __logf(xx));
                if (jj[nj] > i) w = 0.f;
                const unsigned short h = (unsigned short)f2bf(w);
                WT[(size_t)li * 128 + jl[nj]] = h;
                rs += bf2f(h);
            }
            rs += __shfl_down(rs, 8, 16); rs += __shfl_down(rs, 4, 16);
            rs += __shfl_down(rs, 2, 16); rs += __shfl_down(rs, 1, 16);
            if (lm == 0) atomicAdd(&dout[SCR_L + b * NN + i], rs);
        }
}

// =====================================================================
// est_inner: 128x64 tiles (d-quarters, acc[4][2]) -> 480 blocks
// A = raw bf16 w16 (norm deferred), B = V^T; partials -> PART
// =====================================================================
__global__ __launch_bounds__(256) void k_estinner(float* __restrict__ dout) {
    __shared__ short Al[128 * 32];
    __shared__ short Bl[64 * 32];
    const int b = blockIdx.y;
    const int chunk = blockIdx.x >> 2, qd = blockIdx.x & 3;
    int y = chunk, TI = 0, cb = 0;
    for (;;) { const int nc = nc_of(TI); if (y < nc) break; y -= nc; cb += nc; ++TI; }
    const int kbeg = y * 768;
    const int kend = min(kbeg + 768, (TI + 1) * 128);
    const int nst = (kend - kbeg) >> 5;
    const int cidx = cb + y;
    const int tri = TI * (TI + 1) / 2;
    const unsigned short* WT = w16pc(dout, b);
    const unsigned short* VT = u16pc(dout, SCR_B0) + U_VT16 + (size_t)b * DD * NN
                             + (size_t)(qd * 64) * NN;

    const int t = threadIdx.x, wave = t >> 6, lane = t & 63, quad = lane >> 4, lm = lane & 15;
    const int rh = (wave >> 1) * 64, ch = (wave & 1) * 32;

    f32x4 acc[4][2];
#pragma unroll
    for (int i = 0; i < 4; ++i)
#pragma unroll
        for (int j = 0; j < 2; ++j) acc[i][j] = (f32x4){0.f, 0.f, 0.f, 0.f};

    for (int kt = 0; kt < nst; ++kt) {
        const int kk0 = kbeg + kt * 32;
        const int tile = kk0 >> 7;
        stage_tile(WT + (size_t)(tri + tile) * 16384 + (kk0 & 127), 128, Al, t);
        stage64(VT + kk0, NN, Bl, t);
        __syncthreads();
        bf16x8 af[4], bff[2];
#pragma unroll
        for (int mi = 0; mi < 4; ++mi) af[mi] = *(const bf16x8*)&Al[(rh + mi * 16 + lm) * 32 + quad * 8];
#pragma unroll
        for (int nj = 0; nj < 2; ++nj) bff[nj] = *(const bf16x8*)&Bl[(ch + nj * 16 + lm) * 32 + quad * 8];
#pragma unroll
        for (int mi = 0; mi < 4; ++mi)
#pragma unroll
            for (int nj = 0; nj < 2; ++nj)
                acc[mi][nj] = __builtin_amdgcn_mfma_f32_16x16x32_bf16(af[mi], bff[nj], acc[mi][nj], 0, 0, 0);
        __syncthreads();
    }
    unsigned short* P = u16p(dout, SCR_E16F) + U_PART +
                        ((size_t)(b * 30 + cidx)) * 128 * 256;
#pragma unroll
    for (int mi = 0; mi < 4; ++mi)
#pragma unroll
        for (int r = 0; r < 4; ++r) {
            const int ri = rh + mi * 16 + quad * 4 + r;
#pragma unroll
            for (int nj = 0; nj < 2; ++nj) {
                const int d = qd * 64 + ch + nj * 16 + lm;
                P[(size_t)ri * 256 + d] = (unsigned short)f2bf(acc[mi][nj][r]);
            }
        }
}

// =====================================================================
// fused blend + Qij writer + structural fills. grid (2048, 1, 16).
// =====================================================================
__global__ void k_blendfills(float* __restrict__ dout) {
    const int z = blockIdx.z;
    if (z < 4) {
        const int b = z;
        if (blockIdx.x >= 512) return;
        const int t = threadIdx.x;
        const int i = blockIdx.x * 4 + (t >> 6);
        const int d4 = (t & 63) * 4;
        const int TI = i >> 7;
        const int nc = nc_of(TI), cb = cb_of(TI);
        const float s = dout[SCR_SC + 1];
        const float linv = 1.f / dout[SCR_L + b * NN + i];
        const unsigned short* P = u16pc(dout, SCR_E16F) + U_PART;
        float4 sum = {0.f, 0.f, 0.f, 0.f};
        for (int c = 0; c < nc; ++c) {
            ushort4 pv = *(const ushort4*)&P[((size_t)(b * 30 + cb + c) * 128 + (i & 127)) * 256 + d4];
            sum.x += bf2f(pv.x); sum.y += bf2f(pv.y);
            sum.z += bf2f(pv.z); sum.w += bf2f(pv.w);
        }
        const float4 vr = *(const float4*)&dout[OFF_UV + ((size_t)(b * 2) * NN + i) * DD + d4];
        const float sl = s * linv;
        float4 ev;
        ev.x = (1.f - s) * vr.x + sl * sum.x;
        ev.y = (1.f - s) * vr.y + sl * sum.y;
        ev.z = (1.f - s) * vr.z + sl * sum.z;
        ev.w = (1.f - s) * vr.w + sl * sum.w;
        *(float4*)&dout[OFF_EST + ((size_t)(b * 2) * NN + i) * DD + d4] = ev;
        ushort4 o;
        o.x = (unsigned short)f2bf(ev.x); o.y = (unsigned short)f2bf(ev.y);
        o.z = (unsigned short)f2bf(ev.z); o.w = (unsigned short)f2bf(ev.w);
        *(ushort4*)&u16p(dout, SCR_E16F)[((size_t)(b * NN + i)) * 512 + d4] = o;
        return;
    }
    if (z < 8) {
        const int b = z - 4, i = blockIdx.x;
        const int TI = i >> 7, li = i & 127;
        const int tri = TI * (TI + 1) / 2;
        const float linv = 1.f / dout[SCR_L + b * NN + i];
        const unsigned short* WTb = w16pc(dout, b);
        float* row = dout + OFF_QIJ + (size_t)b * 2 * NN * NN + (size_t)i * NN;
        for (int j4 = threadIdx.x * 4; j4 < NN; j4 += 1024) {
            const int tj = j4 >> 7;
            float4 o = {0.f, 0.f, 0.f, 0.f};
            if (tj <= TI) {
                ushort4 h = *(const ushort4*)&WTb[((size_t)(tri + tj)) * 16384
                                                  + (size_t)li * 128 + (j4 & 127)];
                o.x = bf2f(h.x) * linv; o.y = bf2f(h.y) * linv;
                o.z = bf2f(h.z) * linv; o.w = bf2f(h.w) * linv;
            }
            *(float4*)&row[j4] = o;
        }
        return;
    }
    size_t base; long n; float val = 0.f;
    if (z == 8)       { base = SCR_B0; n = 3145728; }
    else if (z == 9)  { base = OFF_VV; n = (long)NN * DD; val = 1.f; }
    else if (z == 10) { base = OFF_VV + (size_t)NN * DD; n = (long)NN * DD; }
    else if (z < 15)  { base = OFF_UV + (size_t)(2 * (z - 11) + 1) * NN * DD; n = (long)NN * DD; }
    else              { base = OFF_LH; n = 512; }
    float* p = dout + base;
    const float4 v = {val, val, val, val};
    for (long i = ((long)blockIdx.x * 256 + threadIdx.x) * 4; i < n;
         i += (long)gridDim.x * 1024)
        *(float4*)&p[i] = v;
}

extern "C" void kernel_launch(void* const* d_in, const int* in_sizes, int n_in,
                              void* d_out, int out_size, void* d_ws, size_t ws_size,
                              hipStream_t stream) {
    const float* Zq = (const float*)d_in[0];
    const float* Zk = (const float*)d_in[1];
    const float* Zv = (const float*)d_in[2];
    const float* tm = (const float*)d_in[3];
    const float* Wq = (const float*)d_in[4];
    const float* bq = (const float*)d_in[5];
    const float* Wk = (const float*)d_in[6];
    const float* bk = (const float*)d_in[7];
    const float* Wv = (const float*)d_in[8];
    const float* bv = (const float*)d_in[9];
    const float* Wp = (const float*)d_in[10];
    const float* bp = (const float*)d_in[11];
    const float* lamOm = (const float*)d_in[13];
    const float* lamGa = (const float*)d_in[14];
    const float* tau = (const float*)d_in[15];
    const float* delta = (const float*)d_in[16];
    const float* lamC = (const float*)d_in[17];
    float* out = (float*)d_out;

    k_cvt<<<dim3(2048, 1, 5), dim3(256), 0, stream>>>(
        Zq, Zk, Zv, Wq, Wk, Wv, Wp, tau, delta, lamOm, lamGa, lamC, out);
    k_qkv<<<dim3(2, 128, 4), dim3(256), 0, stream>>>(bq, bk, bv, out);
    k_vtrans<<<dim3(32, 4, 4), dim3(256), 0, stream>>>(out);
    k_scores<<<dim3(272, 4), dim3(256), 0, stream>>>(tm, out);
    k_estinner<<<dim3(120, 4), dim3(256), 0, stream>>>(out);
    k_blendfills<<<dim3(2048, 1, 16), dim3(256), 0, stream>>>(out);
    k_outproj<<<dim3(2, 128, 2), dim3(256), 0, stream>>>(bp, out);
    // scratch cleanup (Qij imag channels) at fill BW
    hipMemsetAsync((void*)(out + SCR_Z16F),  0, (size_t)NN * NN * 4, stream);
    hipMemsetAsync((void*)(out + SCR_Z16VF), 0, (size_t)NN * NN * 4, stream);
    hipMemsetAsync((void*)(out + SCR_E16F),  0, (size_t)NN * NN * 4, stream);
    hipMemsetAsync((void*)(out + SCR_QN),    0, ((size_t)NN * NN - 3145728) * 4, stream);
}

// Round 7
// 335.713 us; speedup vs baseline: 3.3356x; 1.0344x over previous
//
#include <hip/hip_runtime.h>
#include <math.h>

#define BN 4
#define NN 2048
#define DD 256
#define EPSF 1e-5f

typedef __attribute__((ext_vector_type(8))) short bf16x8;
typedef __attribute__((ext_vector_type(4))) float f32x4;

// ---- output layout (float offsets) ----
constexpr size_t OFF_EST = 0;                                  // (B,2,N,D)
constexpr size_t OFF_OUT = (size_t)BN * 2 * NN * DD;           // (B,2,N,D)
constexpr size_t OFF_QIJ = OFF_OUT + (size_t)BN * 2 * NN * DD; // (B,2,N,N)
constexpr size_t OFF_VV  = OFF_QIJ + (size_t)BN * 2 * NN * NN; // (1,2,N,D)
constexpr size_t OFF_UV  = OFF_VV + (size_t)2 * NN * DD;       // (B,2,N,D)
constexpr size_t OFF_LH  = OFF_UV + (size_t)BN * 2 * NN * DD;  // (2,D,1)

// ---- scratch regions (Q_ij imaginary channels; zeroed before return) ----
constexpr size_t SCR_B0   = OFF_QIJ + (size_t)NN * NN;
constexpr size_t U_Q16    = 0;
constexpr size_t U_K16    = (size_t)BN * NN * DD;
constexpr size_t U_VT16   = 2 * (size_t)BN * NN * DD;
constexpr size_t SCR_QN   = SCR_B0 + 3 * (size_t)BN * NN * DD / 2;
constexpr size_t SCR_KN   = SCR_QN + (size_t)BN * NN;
constexpr size_t SCR_L    = SCR_KN + (size_t)BN * NN;
constexpr size_t SCR_SC   = SCR_L + (size_t)BN * NN;   // [tau2, s, ga_bar, om_bar]
constexpr size_t SCR_W16P = SCR_SC + 16;
constexpr size_t SCR_E16F = OFF_QIJ + 3 * (size_t)NN * NN;
constexpr size_t U_PART   = (size_t)BN * NN * 512;
constexpr size_t SCR_Z16F = OFF_QIJ + 5 * (size_t)NN * NN;
constexpr size_t SCR_Z16VF = OFF_QIJ + 7 * (size_t)NN * NN;
constexpr size_t U_W16    = (size_t)BN * NN * 512;
constexpr size_t W16_PER_B = 136 * 16384;

__device__ __forceinline__ short f2bf(float x) {
    union { float f; unsigned u; } v; v.f = x;
    unsigned r = v.u + 0x7fff + ((v.u >> 16) & 1);
    return (short)(r >> 16);
}
__device__ __forceinline__ float bf2f(unsigned short h) {
    union { unsigned u; float f; } v; v.u = ((unsigned)h) << 16;
    return v.f;
}
__device__ __forceinline__ unsigned short* u16p(float* d, size_t fofs) {
    return (unsigned short*)(d + fofs);
}
__device__ __forceinline__ const unsigned short* u16pc(const float* d, size_t fofs) {
    return (const unsigned short*)(d + fofs);
}
__device__ __forceinline__ unsigned short* w16p(float* d, int b) {
    return (b < 3) ? u16p(d, SCR_Z16F) + (size_t)b * W16_PER_B
                   : u16p(d, SCR_Z16VF);
}
__device__ __forceinline__ const unsigned short* w16pc(const float* d, int b) {
    return (b < 3) ? u16pc(d, SCR_Z16F) + (size_t)b * W16_PER_B
                   : u16pc(d, SCR_Z16VF);
}
__device__ __forceinline__ int nc_of(int TI) { return TI >= 12 ? 3 : (TI >= 6 ? 2 : 1); }
__device__ __forceinline__ int cb_of(int TI) {
    return TI < 6 ? TI : (TI < 12 ? 6 + 2 * (TI - 6) : 18 + 3 * (TI - 12));
}

// async global->LDS, 16B per lane (m97 pattern)
__device__ __forceinline__ void gll16(const unsigned short* g, short* l) {
    __builtin_amdgcn_global_load_lds(
        (const __attribute__((address_space(1))) unsigned*)g,
        (__attribute__((address_space(3))) unsigned*)l, 16, 0, 0);
}
// stage a 128x32 bf16 tile into ldsbuf[128*32] (linear); 2 issues/wave
__device__ __forceinline__ void stage_tile(const unsigned short* gbase, size_t stride_sh,
                                           short* ldsbuf, int t) {
    const int w = t >> 6, L = t & 63;
#pragma unroll
    for (int p = 0; p < 2; ++p) {
        const int r0 = w * 32 + p * 16;
        const unsigned short* src = gbase + (size_t)(r0 + (L >> 2)) * stride_sh + (L & 3) * 8;
        gll16(src, ldsbuf + r0 * 32);
    }
}
// stage a 64x32 bf16 tile into ldsbuf[64*32]; 1 issue/wave
__device__ __forceinline__ void stage64(const unsigned short* gbase, size_t stride_sh,
                                        short* ldsbuf, int t) {
    const int w = t >> 6, L = t & 63;
    const int r0 = w * 16;
    const unsigned short* src = gbase + (size_t)(r0 + (L >> 2)) * stride_sh + (L & 3) * 8;
    gll16(src, ldsbuf + r0 * 32);
}

// =====================================================================
// cvt (+ fused prep): z 0..2 = Z tensors -> bf16 [b][n][512]
// z=3: weights -> 6 bf16 mats [d][512]; z=4: scalars + zero QN/KN/L
// =====================================================================
__global__ void k_cvt(const float* __restrict__ Zq, const float* __restrict__ Zk,
                      const float* __restrict__ Zv,
                      const float* __restrict__ Wq, const float* __restrict__ Wk,
                      const float* __restrict__ Wv, const float* __restrict__ Wp,
                      const float* __restrict__ tau, const float* __restrict__ delta,
                      const float* __restrict__ lamOm, const float* __restrict__ lamGa,
                      const float* __restrict__ lamC,
                      float* __restrict__ dout) {
    const int z = blockIdx.z;
    if (z < 3) {
        const float* Z = (z == 0) ? Zq : (z == 1) ? Zk : Zv;
        unsigned short* O = (z == 0) ? u16p(dout, SCR_Z16F)
                          : (z == 1) ? u16p(dout, SCR_Z16F) + (size_t)BN * NN * 512
                                     : u16p(dout, SCR_Z16VF);
        const long n4 = (long)BN * 2 * NN * DD / 4;
        for (long i4 = (long)blockIdx.x * 256 + threadIdx.x; i4 < n4;
             i4 += (long)gridDim.x * 256) {
            const long i = i4 * 4;
            const int d = (int)(i & (DD - 1));
            const long r = i >> 8;
            const int n = (int)(r & (NN - 1));
            const long bc = r >> 11;
            const int c = (int)(bc & 1), b = (int)(bc >> 1);
            float4 v = *(const float4*)&Z[i];
            ushort4 o;
            o.x = (unsigned short)f2bf(v.x); o.y = (unsigned short)f2bf(v.y);
            o.z = (unsigned short)f2bf(v.z); o.w = (unsigned short)f2bf(v.w);
            *(ushort4*)&O[((size_t)(b * NN + n)) * 512 + c * 256 + d] = o;
        }
    } else if (z == 3) {
        const float* Ws[4] = {Wq, Wk, Wv, Wp};
        const long n4 = 6L * 256 * 512 / 4;
        for (long e4 = (long)blockIdx.x * 256 + threadIdx.x; e4 < n4;
             e4 += (long)gridDim.x * 256) {
            const long e = e4 * 4;
            const int k = (int)(e & 511);
            const long rest = e >> 9;
            const int dd = (int)(rest & 255);
            const int m = (int)(rest >> 8);
            int proj, mode;
            if (m < 3)      { proj = m; mode = 0; }
            else if (m == 3){ proj = 2; mode = 1; }
            else            { proj = 3; mode = m - 4; }
            const int kc = k >> 8, kk = k & 255;
            int wc; float sgn;
            if (mode == 0) { wc = kc; sgn = kc ? -1.f : 1.f; }
            else           { wc = 1 - kc; sgn = 1.f; }
            float4 v = *(const float4*)&Ws[proj][((size_t)wc * DD + dd) * DD + kk];
            ushort4 o;
            o.x = (unsigned short)f2bf(sgn * v.x); o.y = (unsigned short)f2bf(sgn * v.y);
            o.z = (unsigned short)f2bf(sgn * v.z); o.w = (unsigned short)f2bf(sgn * v.w);
            unsigned short* dst = (m < 4)
                ? u16p(dout, SCR_Z16VF) + U_W16 + (size_t)m * 131072
                : u16p(dout, SCR_W16P) + (size_t)(m - 4) * 131072;
            *(ushort4*)&dst[(size_t)dd * 512 + k] = o;
        }
    } else {
        const int idx = blockIdx.x * 256 + threadIdx.x;
        if (idx < 3 * BN * NN) dout[SCR_QN + idx] = 0.f;
        if (blockIdx.x == 0) {
            __shared__ float red[8];
            const int t = threadIdx.x;
            float c2 = lamC[t] * lamC[t];
            float ga = c2 * (lamGa[t] * lamGa[t] + EPSF);
            float om = c2 * (lamOm[t] * lamOm[t] + EPSF);
            for (int o = 32; o > 0; o >>= 1) {
                ga += __shfl_down(ga, o, 64);
                om += __shfl_down(om, o, 64);
            }
            if ((t & 63) == 0) { red[t >> 6] = ga; red[4 + (t >> 6)] = om; }
            __syncthreads();
            if (t == 0) {
                float gs = red[0] + red[1] + red[2] + red[3];
                float os = red[4] + red[5] + red[6] + red[7];
                float* scal = dout + SCR_SC;
                scal[0] = tau[0] * tau[0];
                scal[1] = 1.f / (1.f + __expf(-delta[0]));
                scal[2] = gs / 256.f;
                scal[3] = os / 256.f;
            }
        }
    }
}

// =====================================================================
// QKV projection, 64x128 tiles (acc[2][4]) -> 1024 blocks
// z: 0=Qr->Q16(+QN), 1=Kr->K16(+KN), 2=Vr->UVch0, 3=Vi->est ch1 + E16 ch1
// =====================================================================
__global__ __launch_bounds__(256) void k_qkv(const float* __restrict__ bq,
                                             const float* __restrict__ bk,
                                             const float* __restrict__ bv,
                                             float* __restrict__ dout)
{
    __shared__ short Al[64 * 32];
    __shared__ short Bl[128 * 32];
    const int z = blockIdx.z;
    const int d0 = blockIdx.x * 128;
    const int b = blockIdx.y >> 5;
    const int n0 = (blockIdx.y & 31) * 64;

    const unsigned short* Z16 =
        (z == 0) ? u16pc(dout, SCR_Z16F)
      : (z == 1) ? u16pc(dout, SCR_Z16F) + (size_t)BN * NN * 512
                 : u16pc(dout, SCR_Z16VF);
    const unsigned short* W16 = u16pc(dout, SCR_Z16VF) + U_W16 + (size_t)z * 131072;
    const float* bias = (z == 0) ? bq : (z == 1) ? bk : bv;
    const int bofs = (z == 3) ? DD : 0;

    const int t = threadIdx.x, wave = t >> 6, lane = t & 63, quad = lane >> 4, lm = lane & 15;
    const int wr = (wave >> 1) * 32, wc = (wave & 1) * 64;
    const unsigned short* Abase = Z16 + (size_t)(b * NN + n0) * 512;
    const unsigned short* Bbase = W16 + (size_t)d0 * 512;

    f32x4 acc[2][4];
#pragma unroll
    for (int i = 0; i < 2; ++i)
#pragma unroll
        for (int j = 0; j < 4; ++j) acc[i][j] = (f32x4){0.f, 0.f, 0.f, 0.f};

    for (int kt = 0; kt < 16; ++kt) {
        const int kk0 = kt * 32;
        stage64(Abase + kk0, 512, Al, t);
        stage_tile(Bbase + kk0, 512, Bl, t);
        __syncthreads();
        bf16x8 af[2], bff[4];
#pragma unroll
        for (int mi = 0; mi < 2; ++mi) af[mi] = *(const bf16x8*)&Al[(wr + mi * 16 + lm) * 32 + quad * 8];
#pragma unroll
        for (int nj = 0; nj < 4; ++nj) bff[nj] = *(const bf16x8*)&Bl[(wc + nj * 16 + lm) * 32 + quad * 8];
#pragma unroll
        for (int mi = 0; mi < 2; ++mi)
#pragma unroll
            for (int nj = 0; nj < 4; ++nj)
                acc[mi][nj] = __builtin_amdgcn_mfma_f32_16x16x32_bf16(af[mi], bff[nj], acc[mi][nj], 0, 0, 0);
        __syncthreads();
    }

    if (z <= 1) {
        unsigned short* O16 = u16p(dout, SCR_B0) + (z ? U_K16 : U_Q16) + (size_t)b * NN * DD;
        float* NRM = dout + (z ? SCR_KN : SCR_QN) + b * NN;
#pragma unroll
        for (int mi = 0; mi < 2; ++mi)
#pragma unroll
            for (int r = 0; r < 4; ++r) {
                const int m = n0 + wr + mi * 16 + quad * 4 + r;
                float ss = 0.f;
#pragma unroll
                for (int nj = 0; nj < 4; ++nj) {
                    const int d = d0 + wc + nj * 16 + lm;
                    unsigned short h = (unsigned short)f2bf(acc[mi][nj][r] + bias[d]);
                    O16[(size_t)m * DD + d] = h;
                    const float vb = bf2f(h);
                    ss = fmaf(vb, vb, ss);
                }
                ss += __shfl_down(ss, 8, 16); ss += __shfl_down(ss, 4, 16);
                ss += __shfl_down(ss, 2, 16); ss += __shfl_down(ss, 1, 16);
                if (lm == 0) atomicAdd(&NRM[m], ss);
            }
    } else if (z == 2) {
        float* UV0 = dout + OFF_UV + (size_t)(b * 2) * NN * DD;
#pragma unroll
        for (int mi = 0; mi < 2; ++mi)
#pragma unroll
            for (int r = 0; r < 4; ++r) {
                const int m = n0 + wr + mi * 16 + quad * 4 + r;
#pragma unroll
                for (int nj = 0; nj < 4; ++nj) {
                    const int d = d0 + wc + nj * 16 + lm;
                    UV0[(size_t)m * DD + d] = acc[mi][nj][r] + bias[d];
                }
            }
    } else {
        const float s1 = 1.f - dout[SCR_SC + 1];
        float* EST1 = dout + OFF_EST + (size_t)(b * 2 + 1) * NN * DD;
        unsigned short* E16 = u16p(dout, SCR_E16F) + (size_t)b * NN * 512;
#pragma unroll
        for (int mi = 0; mi < 2; ++mi)
#pragma unroll
            for (int r = 0; r < 4; ++r) {
                const int m = n0 + wr + mi * 16 + quad * 4 + r;
#pragma unroll
                for (int nj = 0; nj < 4; ++nj) {
                    const int d = d0 + wc + nj * 16 + lm;
                    const float v = s1 * (acc[mi][nj][r] + bias[bofs + d]);
                    EST1[(size_t)m * DD + d] = v;
                    E16[(size_t)m * 512 + 256 + d] = (unsigned short)f2bf(v);
                }
            }
    }
}

// =====================================================================
// output projection, 64x128 tiles; z==2 slice zeros b2/b3-imag (w16,
// dead after blendfills) concurrently with the GEMM
// =====================================================================
__global__ __launch_bounds__(256) void k_outproj(const float* __restrict__ bp,
                                                 float* __restrict__ dout)
{
    __shared__ short Al[64 * 32];
    __shared__ short Bl[128 * 32];
    const int z = blockIdx.z;
    if (z == 2) {
        const long idx = (long)(blockIdx.y * 2 + blockIdx.x) * 256 + threadIdx.x;
        const float4 zz4 = {0.f, 0.f, 0.f, 0.f};
        for (long u = idx * 4; u < (long)NN * NN; u += 256L * 256 * 4) {
            *(float4*)&dout[SCR_Z16F + u] = zz4;
            *(float4*)&dout[SCR_Z16VF + u] = zz4;
        }
        return;
    }
    const int d0 = blockIdx.x * 128;
    const int b = blockIdx.y >> 5;
    const int n0 = (blockIdx.y & 31) * 64;
    const unsigned short* E16 = u16pc(dout, SCR_E16F) + (size_t)b * NN * 512;
    const unsigned short* W16 = u16pc(dout, SCR_W16P) + (size_t)z * 131072;

    const int t = threadIdx.x, wave = t >> 6, lane = t & 63, quad = lane >> 4, lm = lane & 15;
    const int wr = (wave >> 1) * 32, wc = (wave & 1) * 64;
    const unsigned short* Abase = E16 + (size_t)n0 * 512;
    const unsigned short* Bbase = W16 + (size_t)d0 * 512;

    f32x4 acc[2][4];
#pragma unroll
    for (int i = 0; i < 2; ++i)
#pragma unroll
        for (int j = 0; j < 4; ++j) acc[i][j] = (f32x4){0.f, 0.f, 0.f, 0.f};

    for (int kt = 0; kt < 16; ++kt) {
        const int kk0 = kt * 32;
        stage64(Abase + kk0, 512, Al, t);
        stage_tile(Bbase + kk0, 512, Bl, t);
        __syncthreads();
        bf16x8 af[2], bff[4];
#pragma unroll
        for (int mi = 0; mi < 2; ++mi) af[mi] = *(const bf16x8*)&Al[(wr + mi * 16 + lm) * 32 + quad * 8];
#pragma unroll
        for (int nj = 0; nj < 4; ++nj) bff[nj] = *(const bf16x8*)&Bl[(wc + nj * 16 + lm) * 32 + quad * 8];
#pragma unroll
        for (int mi = 0; mi < 2; ++mi)
#pragma unroll
            for (int nj = 0; nj < 4; ++nj)
                acc[mi][nj] = __builtin_amdgcn_mfma_f32_16x16x32_bf16(af[mi], bff[nj], acc[mi][nj], 0, 0, 0);
        __syncthreads();
    }
    const int bofs = z ? DD : 0;
    float* O = dout + OFF_OUT + (size_t)(b * 2 + z) * NN * DD;
#pragma unroll
    for (int mi = 0; mi < 2; ++mi)
#pragma unroll
        for (int r = 0; r < 4; ++r) {
            const int m = n0 + wr + mi * 16 + quad * 4 + r;
#pragma unroll
            for (int nj = 0; nj < 4; ++nj) {
                const int d = d0 + wc + nj * 16 + lm;
                O[(size_t)m * DD + d] = acc[mi][nj][r] + bp[bofs + d];
            }
        }
}

// =====================================================================
// causal scores, 64x128 i-half tiles (x < 272) + fused V-transpose
// (x >= 272: UV ch0 [b][n][d] fp32 -> VT16 [b][d][n] bf16)
// =====================================================================
__global__ __launch_bounds__(256) void k_scores(const float* __restrict__ tmeas,
                                                float* __restrict__ dout) {
    __shared__ __align__(16) float smemf[4160];  // 16.6KB: Al|Bl (12KB) or T[64][65]
    short* Al = (short*)smemf;
    short* Bl = ((short*)smemf) + 2048;
    const int b = blockIdx.y;
    if (blockIdx.x >= 272) {
        // ---- V transpose job ----
        float (*T)[65] = (float(*)[65])smemf;
        const int vj = blockIdx.x - 272;
        const int nb = (vj & 31) * 64, db = (vj >> 5) * 64;
        const float* V = dout + OFF_UV + (size_t)(b * 2) * NN * DD;
        unsigned short* VT = u16p(dout, SCR_B0) + U_VT16 + (size_t)b * DD * NN;
        const int tr = threadIdx.x >> 4, tc = (threadIdx.x & 15) * 4;
#pragma unroll
        for (int p = 0; p < 4; ++p) {
            float4 v = *(const float4*)&V[(size_t)(nb + tr + p * 16) * DD + db + tc];
            T[tr + p * 16][tc + 0] = v.x; T[tr + p * 16][tc + 1] = v.y;
            T[tr + p * 16][tc + 2] = v.z; T[tr + p * 16][tc + 3] = v.w;
        }
        __syncthreads();
#pragma unroll
        for (int p = 0; p < 4; ++p) {
            const int d = tr + p * 16;
            ushort4 o;
            o.x = (unsigned short)f2bf(T[tc + 0][d]);
            o.y = (unsigned short)f2bf(T[tc + 1][d]);
            o.z = (unsigned short)f2bf(T[tc + 2][d]);
            o.w = (unsigned short)f2bf(T[tc + 3][d]);
            *(ushort4*)&VT[(size_t)(db + d) * NN + nb + tc] = o;
        }
        return;
    }
    const int x2 = blockIdx.x;
    const int x = x2 >> 1, ih = x2 & 1;
    int ti = (int)((sqrtf(8.f * x + 1.f) - 1.f) * 0.5f);
    while ((ti + 1) * (ti + 2) / 2 <= x) ++ti;
    while (ti * (ti + 1) / 2 > x) --ti;
    const int tj = x - ti * (ti + 1) / 2;
    const int i0 = ti * 128, j0 = tj * 128;
    const int ib = i0 + ih * 64;
    const unsigned short* Q16 = u16pc(dout, SCR_B0) + U_Q16 + (size_t)b * NN * DD;
    const unsigned short* K16 = u16pc(dout, SCR_B0) + U_K16 + (size_t)b * NN * DD;
    const int t = threadIdx.x, wave = t >> 6, lane = t & 63, quad = lane >> 4, lm = lane & 15;
    const int wr = (wave >> 1) * 32, wc = (wave & 1) * 64;
    const unsigned short* Abase = Q16 + (size_t)ib * DD;
    const unsigned short* Bbase = K16 + (size_t)j0 * DD;

    f32x4 acc[2][4];
#pragma unroll
    for (int i = 0; i < 2; ++i)
#pragma unroll
        for (int j = 0; j < 4; ++j) acc[i][j] = (f32x4){0.f, 0.f, 0.f, 0.f};

    for (int kt = 0; kt < 8; ++kt) {
        const int kk0 = kt * 32;
        stage64(Abase + kk0, DD, Al, t);
        stage_tile(Bbase + kk0, DD, Bl, t);
        __syncthreads();
        bf16x8 af[2], bff[4];
#pragma unroll
        for (int mi = 0; mi < 2; ++mi) af[mi] = *(const bf16x8*)&Al[(wr + mi * 16 + lm) * 32 + quad * 8];
#pragma unroll
        for (int nj = 0; nj < 4; ++nj) bff[nj] = *(const bf16x8*)&Bl[(wc + nj * 16 + lm) * 32 + quad * 8];
#pragma unroll
        for (int mi = 0; mi < 2; ++mi)
#pragma unroll
            for (int nj = 0; nj < 4; ++nj)
                acc[mi][nj] = __builtin_amdgcn_mfma_f32_16x16x32_bf16(af[mi], bff[nj], acc[mi][nj], 0, 0, 0);
        __syncthreads();
    }

    const float tau2 = dout[SCR_SC + 0], ga = dout[SCR_SC + 2], om = dout[SCR_SC + 3];
    unsigned short* WT = w16p(dout, b) + (size_t)x * 16384;
    const float* QN_ = dout + SCR_QN + b * NN;
    const float* KN_ = dout + SCR_KN + b * NN;
    float kn[4], tjv[4]; int jj[4], jl[4];
#pragma unroll
    for (int nj = 0; nj < 4; ++nj) {
        jl[nj] = wc + nj * 16 + lm;
        jj[nj] = j0 + jl[nj];
        kn[nj] = KN_[jj[nj]];
        tjv[nj] = tmeas[jj[nj]];
    }
#pragma unroll
    for (int mi = 0; mi < 2; ++mi)
#pragma unroll
        for (int r = 0; r < 4; ++r) {
            const int li = ih * 64 + wr + mi * 16 + quad * 4 + r;
            const int i = i0 + li;
            const float qni = QN_[i], tqi = tmeas[i];
            float rs = 0.f;
#pragma unroll
            for (int nj = 0; nj < 4; ++nj) {
                float xx = ga + om * fabsf(tqi - tjv[nj]) + qni + kn[nj] - 2.f * acc[mi][nj][r];
                xx = fmaxf(xx, 1e-30f);
                float w = (tau2 == 1.f) ? __builtin_amdgcn_rcpf(xx)
                                        : __expf(-tau2 * __logf(xx));
                if (jj[nj] > i) w = 0.f;
                const unsigned short h = (unsigned short)f2bf(w);
                WT[(size_t)li * 128 + jl[nj]] = h;
                rs += bf2f(h);
            }
            rs += __shfl_down(rs, 8, 16); rs += __shfl_down(rs, 4, 16);
            rs += __shfl_down(rs, 2, 16); rs += __shfl_down(rs, 1, 16);
            if (lm == 0) atomicAdd(&dout[SCR_L + b * NN + i], rs);
        }
}

// =====================================================================
// est_inner: 128x64 tiles (d-quarters, acc[4][2]) -> 480 blocks
// A = raw bf16 w16 (norm deferred), B = V^T; partials -> PART
// =====================================================================
__global__ __launch_bounds__(256) void k_estinner(float* __restrict__ dout) {
    __shared__ short Al[128 * 32];
    __shared__ short Bl[64 * 32];
    const int b = blockIdx.y;
    const int chunk = blockIdx.x >> 2, qd = blockIdx.x & 3;
    int y = chunk, TI = 0, cb = 0;
    for (;;) { const int nc = nc_of(TI); if (y < nc) break; y -= nc; cb += nc; ++TI; }
    const int kbeg = y * 768;
    const int kend = min(kbeg + 768, (TI + 1) * 128);
    const int nst = (kend - kbeg) >> 5;
    const int cidx = cb + y;
    const int tri = TI * (TI + 1) / 2;
    const unsigned short* WT = w16pc(dout, b);
    const unsigned short* VT = u16pc(dout, SCR_B0) + U_VT16 + (size_t)b * DD * NN
                             + (size_t)(qd * 64) * NN;

    const int t = threadIdx.x, wave = t >> 6, lane = t & 63, quad = lane >> 4, lm = lane & 15;
    const int rh = (wave >> 1) * 64, ch = (wave & 1) * 32;

    f32x4 acc[4][2];
#pragma unroll
    for (int i = 0; i < 4; ++i)
#pragma unroll
        for (int j = 0; j < 2; ++j) acc[i][j] = (f32x4){0.f, 0.f, 0.f, 0.f};

    for (int kt = 0; kt < nst; ++kt) {
        const int kk0 = kbeg + kt * 32;
        const int tile = kk0 >> 7;
        stage_tile(WT + (size_t)(tri + tile) * 16384 + (kk0 & 127), 128, Al, t);
        stage64(VT + kk0, NN, Bl, t);
        __syncthreads();
        bf16x8 af[4], bff[2];
#pragma unroll
        for (int mi = 0; mi < 4; ++mi) af[mi] = *(const bf16x8*)&Al[(rh + mi * 16 + lm) * 32 + quad * 8];
#pragma unroll
        for (int nj = 0; nj < 2; ++nj) bff[nj] = *(const bf16x8*)&Bl[(ch + nj * 16 + lm) * 32 + quad * 8];
#pragma unroll
        for (int mi = 0; mi < 4; ++mi)
#pragma unroll
            for (int nj = 0; nj < 2; ++nj)
                acc[mi][nj] = __builtin_amdgcn_mfma_f32_16x16x32_bf16(af[mi], bff[nj], acc[mi][nj], 0, 0, 0);
        __syncthreads();
    }
    unsigned short* P = u16p(dout, SCR_E16F) + U_PART +
                        ((size_t)(b * 30 + cidx)) * 128 * 256;
#pragma unroll
    for (int mi = 0; mi < 4; ++mi)
#pragma unroll
        for (int r = 0; r < 4; ++r) {
            const int ri = rh + mi * 16 + quad * 4 + r;
#pragma unroll
            for (int nj = 0; nj < 2; ++nj) {
                const int d = qd * 64 + ch + nj * 16 + lm;
                P[(size_t)ri * 256 + d] = (unsigned short)f2bf(acc[mi][nj][r]);
            }
        }
}

// =====================================================================
// fused blend + Qij writer + structural fills. grid (2048, 1, 16).
// =====================================================================
__global__ void k_blendfills(float* __restrict__ dout) {
    const int z = blockIdx.z;
    if (z < 4) {
        const int b = z;
        if (blockIdx.x >= 512) return;
        const int t = threadIdx.x;
        const int i = blockIdx.x * 4 + (t >> 6);
        const int d4 = (t & 63) * 4;
        const int TI = i >> 7;
        const int nc = nc_of(TI), cb = cb_of(TI);
        const float s = dout[SCR_SC + 1];
        const float linv = 1.f / dout[SCR_L + b * NN + i];
        const unsigned short* P = u16pc(dout, SCR_E16F) + U_PART;
        float4 sum = {0.f, 0.f, 0.f, 0.f};
        for (int c = 0; c < nc; ++c) {
            ushort4 pv = *(const ushort4*)&P[((size_t)(b * 30 + cb + c) * 128 + (i & 127)) * 256 + d4];
            sum.x += bf2f(pv.x); sum.y += bf2f(pv.y);
            sum.z += bf2f(pv.z); sum.w += bf2f(pv.w);
        }
        const float4 vr = *(const float4*)&dout[OFF_UV + ((size_t)(b * 2) * NN + i) * DD + d4];
        const float sl = s * linv;
        float4 ev;
        ev.x = (1.f - s) * vr.x + sl * sum.x;
        ev.y = (1.f - s) * vr.y + sl * sum.y;
        ev.z = (1.f - s) * vr.z + sl * sum.z;
        ev.w = (1.f - s) * vr.w + sl * sum.w;
        *(float4*)&dout[OFF_EST + ((size_t)(b * 2) * NN + i) * DD + d4] = ev;
        ushort4 o;
        o.x = (unsigned short)f2bf(ev.x); o.y = (unsigned short)f2bf(ev.y);
        o.z = (unsigned short)f2bf(ev.z); o.w = (unsigned short)f2bf(ev.w);
        *(ushort4*)&u16p(dout, SCR_E16F)[((size_t)(b * NN + i)) * 512 + d4] = o;
        return;
    }
    if (z < 8) {
        const int b = z - 4, i = blockIdx.x;
        const int TI = i >> 7, li = i & 127;
        const int tri = TI * (TI + 1) / 2;
        const float linv = 1.f / dout[SCR_L + b * NN + i];
        const unsigned short* WTb = w16pc(dout, b);
        float* row = dout + OFF_QIJ + (size_t)b * 2 * NN * NN + (size_t)i * NN;
        for (int j4 = threadIdx.x * 4; j4 < NN; j4 += 1024) {
            const int tj = j4 >> 7;
            float4 o = {0.f, 0.f, 0.f, 0.f};
            if (tj <= TI) {
                ushort4 h = *(const ushort4*)&WTb[((size_t)(tri + tj)) * 16384
                                                  + (size_t)li * 128 + (j4 & 127)];
                o.x = bf2f(h.x) * linv; o.y = bf2f(h.y) * linv;
                o.z = bf2f(h.z) * linv; o.w = bf2f(h.w) * linv;
            }
            *(float4*)&row[j4] = o;
        }
        return;
    }
    size_t base; long n; float val = 0.f;
    if (z == 8)       { base = SCR_B0; n = 3145728; }
    else if (z == 9)  { base = OFF_VV; n = (long)NN * DD; val = 1.f; }
    else if (z == 10) { base = OFF_VV + (size_t)NN * DD; n = (long)NN * DD; }
    else if (z < 15)  { base = OFF_UV + (size_t)(2 * (z - 11) + 1) * NN * DD; n = (long)NN * DD; }
    else              { base = OFF_LH; n = 512; }
    float* p = dout + base;
    const float4 v = {val, val, val, val};
    for (long i = ((long)blockIdx.x * 256 + threadIdx.x) * 4; i < n;
         i += (long)gridDim.x * 1024)
        *(float4*)&p[i] = v;
}

// zero b1-imag (E16+PART) and b0 tail (QN/KN/L/SC/W16P) after outproj
__global__ void k_tail(float* __restrict__ dout) {
    const float4 zz = {0.f, 0.f, 0.f, 0.f};
    const long n1 = (long)NN * NN;
    for (long i = ((long)blockIdx.x * 256 + threadIdx.x) * 4; i < n1;
         i += (long)gridDim.x * 1024)
        *(float4*)&dout[SCR_E16F + i] = zz;
    const long n0 = (long)NN * NN - 3145728;  // 1048576 floats
    for (long i = ((long)blockIdx.x * 256 + threadIdx.x) * 4; i < n0;
         i += (long)gridDim.x * 1024)
        *(float4*)&dout[SCR_QN + i] = zz;
}

extern "C" void kernel_launch(void* const* d_in, const int* in_sizes, int n_in,
                              void* d_out, int out_size, void* d_ws, size_t ws_size,
                              hipStream_t stream) {
    const float* Zq = (const float*)d_in[0];
    const float* Zk = (const float*)d_in[1];
    const float* Zv = (const float*)d_in[2];
    const float* tm = (const float*)d_in[3];
    const float* Wq = (const float*)d_in[4];
    const float* bq = (const float*)d_in[5];
    const float* Wk = (const float*)d_in[6];
    const float* bk = (const float*)d_in[7];
    const float* Wv = (const float*)d_in[8];
    const float* bv = (const float*)d_in[9];
    const float* Wp = (const float*)d_in[10];
    const float* bp = (const float*)d_in[11];
    const float* lamOm = (const float*)d_in[13];
    const float* lamGa = (const float*)d_in[14];
    const float* tau = (const float*)d_in[15];
    const float* delta = (const float*)d_in[16];
    const float* lamC = (const float*)d_in[17];
    float* out = (float*)d_out;

    k_cvt<<<dim3(2048, 1, 5), dim3(256), 0, stream>>>(
        Zq, Zk, Zv, Wq, Wk, Wv, Wp, tau, delta, lamOm, lamGa, lamC, out);
    k_qkv<<<dim3(2, 128, 4), dim3(256), 0, stream>>>(bq, bk, bv, out);
    k_scores<<<dim3(400, 4), dim3(256), 0, stream>>>(tm, out);   // + fused vtrans
    k_estinner<<<dim3(120, 4), dim3(256), 0, stream>>>(out);
    k_blendfills<<<dim3(2048, 1, 16), dim3(256), 0, stream>>>(out);
    k_outproj<<<dim3(2, 128, 3), dim3(256), 0, stream>>>(bp, out); // + w16 zero slice
    k_tail<<<dim3(1024), dim3(256), 0, stream>>>(out);
}